// Round 10
// baseline (22323.590 us; speedup 1.0000x reference)
//
#include <hip/hip_runtime.h>
#include <hip/hip_bf16.h>

// TGCN: B=64, T=500, N=21, HID=128.
// Round 17: r8 column-split structure + working ILP.
// Model (reconciled over r7-r16): r7/r16 (12.5ms) is bounded by L1 data
// return (~2.36MB/tick/CU delivered, 4x wave redundancy, ~15us) + VALU 7us.
// r8's column-split cut delivered bytes 4x but exposed L2 latency with a
// rolled 1-iteration-in-flight loop (40us/tick). This round adds the ILP
// that r9-r12 failed to add (scratch disasters from address-taken arrays /
// conditional aggregate PHIs):
//   (1) __launch_bounds__(512,1): 256-VGPR budget (r16 proved harmless).
//   (2) #pragma unroll 2 on weight c-loops -- straight-line SSA, scheduler
//       hoists next iteration's loads over current compute. No arrays.
//   (3) P4 as two per-pair passes (10 loads/iter); consts in LDS sVec.
// All accumulator chains keep exact c-ascending intra-c order -> absmax 0.0.
// NEVER reorder per-element sums in the recurrence.

#define NN 21
#define NROW 24            // padded rows (21,22,23 zero)
#define S 132              // padded float stride for H arrays (132%32==4)
#define SV4 33             // float4 stride
#define HID 128
#define TSTEPS 500
#define EDGES 210
#define NTHREADS 512       // 8 waves: 4 per group
#define RPT 3              // rows per row-group

// ws layout (float offsets) — unchanged
#define WS_A     0
#define WS_VEC   1600
#define WS_LZR1  3200
#define WS_LH1   36000
#define WS_WE2   52400
#define WS_LZR2  101600
#define WS_LH2   134400

typedef float v2f __attribute__((ext_vector_type(2)));

template<int N> struct ic { static constexpr int v = N; };

__device__ __forceinline__ v2f lo2(float4 w) { v2f v = {w.x, w.y}; return v; }
__device__ __forceinline__ v2f hi2(float4 w) { v2f v = {w.z, w.w}; return v; }
__device__ __forceinline__ void pkf(v2f& acc, float s, v2f w) {
    v2f ss = {s, s};
    acc = __builtin_elementwise_fma(ss, w, acc);
}
__device__ __forceinline__ float sigmoidf(float v) {
    return 1.0f / (1.0f + expf(-v));
}

// ---- Prologue: build normalized adjacency A (21x21) in fp64, store fp32 ----
__global__ void build_A(const int* __restrict__ ei, const float* __restrict__ ew,
                        float* __restrict__ Aout) {
    __shared__ double deg[NN];
    __shared__ double dinv[NN];
    __shared__ double Asm[NN * NN];
    int t = threadIdx.x;
    for (int k = t; k < NN * NN; k += blockDim.x) Asm[k] = 0.0;
    if (t < NN) deg[t] = 1.0;  // self loop weight 1
    __syncthreads();
    if (t == 0) {
        for (int e = 0; e < EDGES; e++) deg[ei[EDGES + e]] += (double)ew[e];
        for (int i = 0; i < NN; i++) dinv[i] = deg[i] > 0.0 ? 1.0 / sqrt(deg[i]) : 0.0;
        for (int e = 0; e < EDGES; e++) {
            int s = ei[e], d = ei[EDGES + e];
            Asm[d * NN + s] += dinv[s] * (double)ew[e] * dinv[d];
        }
        for (int i = 0; i < NN; i++) Asm[i * NN + i] += dinv[i] * dinv[i];
    }
    __syncthreads();
    for (int k = t; k < NROW * NN; k += blockDim.x)
        Aout[k] = (k < NN * NN) ? (float)Asm[k] : 0.0f;
}

// ---- Prologue: repack bottom halves of (256,128) concat weights ----------
__global__ void pack_bot(const float* __restrict__ w0, const float* __restrict__ w1,
                         float4* __restrict__ out, int ngate) {
    int t = blockIdx.x * blockDim.x + threadIdx.x;
    int per_c = ngate * 128;
    int total = 32 * per_c;
    if (t >= total) return;
    int c = t / per_c, rem = t - c * per_c;
    int gate = rem >> 7;
    int r2 = rem & 127;
    int k2 = r2 >> 6;
    int f0 = r2 & 63;
    int k = 4 * c + 2 * k2;
    const float* src = (gate == 0) ? w0 : w1;
    float4 v;
    v.x = src[(128 + k) * 128 + f0];
    v.y = src[(128 + k) * 128 + f0 + 64];
    v.z = src[(128 + k + 1) * 128 + f0];
    v.w = src[(128 + k + 1) * 128 + f0 + 64];
    out[t] = v;
}

// ---- Prologue: Weff2_g = Wg_2 @ lgw_2_top, pair-interleaved, fp64 accum ----
__global__ void make_weff2(const float* __restrict__ Wz2, const float* __restrict__ Wr2,
                           const float* __restrict__ Wh2,
                           const float* __restrict__ lzw2, const float* __restrict__ lrw2,
                           const float* __restrict__ lhw2,
                           float4* __restrict__ out) {
    int t = blockIdx.x * blockDim.x + threadIdx.x;
    if (t >= 32 * 384) return;
    int c = t / 384, rem = t - c * 384;
    int g = rem >> 7;
    int r2 = rem & 127;
    int k2 = r2 >> 6;
    int f0 = r2 & 63;
    int k = 4 * c + 2 * k2;
    const float* W = (g == 0) ? Wz2 : (g == 1) ? Wr2 : Wh2;
    const float* L = (g == 0) ? lzw2 : (g == 1) ? lrw2 : lhw2;
    double a0 = 0, a1 = 0, a2 = 0, a3 = 0;
    for (int m = 0; m < 128; m++) {
        double w0 = (double)W[k * 128 + m];
        double w1 = (double)W[(k + 1) * 128 + m];
        a0 += w0 * (double)L[m * 128 + f0];
        a1 += w0 * (double)L[m * 128 + f0 + 64];
        a2 += w1 * (double)L[m * 128 + f0];
        a3 += w1 * (double)L[m * 128 + f0 + 64];
    }
    out[t] = make_float4((float)a0, (float)a1, (float)a2, (float)a3);
}

// ---- Prologue: layer-1 effective row vectors + all bias consts (fp64) ----
__global__ void make_vecs(const float* __restrict__ Wz1, const float* __restrict__ Wr1,
                          const float* __restrict__ Wh1,
                          const float* __restrict__ bz1, const float* __restrict__ br1,
                          const float* __restrict__ bh1,
                          const float* __restrict__ lzw1, const float* __restrict__ lrw1,
                          const float* __restrict__ lhw1,
                          const float* __restrict__ lzb1, const float* __restrict__ lrb1,
                          const float* __restrict__ lhb1,
                          const float* __restrict__ bz2, const float* __restrict__ br2,
                          const float* __restrict__ bh2,
                          const float* __restrict__ lzw2, const float* __restrict__ lrw2,
                          const float* __restrict__ lhw2,
                          const float* __restrict__ lzb2, const float* __restrict__ lrb2,
                          const float* __restrict__ lhb2,
                          float* __restrict__ out) {
    int t = blockIdx.x * blockDim.x + threadIdx.x;
    if (t >= 9 * 128) return;
    int v = t >> 7, f = t & 127;
    double acc = 0.0;
    if (v < 3) {
        const float* W = (v == 0) ? Wz1 : (v == 1) ? Wr1 : Wh1;
        const float* L = (v == 0) ? lzw1 : (v == 1) ? lrw1 : lhw1;
        for (int m = 0; m < 128; m++) acc += (double)W[m] * (double)L[m * 128 + f];
    } else if (v < 6) {
        int g = v - 3;
        const float* bb = (g == 0) ? bz1 : (g == 1) ? br1 : bh1;
        const float* L  = (g == 0) ? lzw1 : (g == 1) ? lrw1 : lhw1;
        const float* lb = (g == 0) ? lzb1 : (g == 1) ? lrb1 : lhb1;
        for (int m = 0; m < 128; m++) acc += (double)bb[m] * (double)L[m * 128 + f];
        acc += (double)lb[f];
    } else {
        int g = v - 6;
        const float* bb = (g == 0) ? bz2 : (g == 1) ? br2 : bh2;
        const float* L  = (g == 0) ? lzw2 : (g == 1) ? lrw2 : lhw2;
        const float* lb = (g == 0) ? lzb2 : (g == 1) ? lrb2 : lhb2;
        for (int m = 0; m < 128; m++) acc += (double)bb[m] * (double)L[m * 128 + f];
        acc += (double)lb[f];
    }
    out[t] = (float)acc;
}

// ---- Main: one block per batch, layer-pipelined groups, 2 barriers/tick ----
__global__ __launch_bounds__(NTHREADS, 1) void tgcn_main(
    const float* __restrict__ x,       // (64,500,21)
    const float* __restrict__ ws,
    const float* __restrict__ cls_w,   // (128,1)
    const float* __restrict__ cls_b,   // (1,)
    float* __restrict__ out)           // (64,)
{
    const int b  = blockIdx.x;
    const int t  = threadIdx.x;
    const bool isA = (t < 256);                              // wave-uniform
    const int lt = t & 255;
    const int gw = __builtin_amdgcn_readfirstlane(lt >> 6);  // wave in group 0..3
    const int lane = t & 63;
    const int p  = lane & 7;          // pair slot
    const int rg = lane >> 3;         // row group 0..7
    const int rb = rg * RPT;          // first row of this lane
    const int f0A = gw * 16 + p;      // first pair:  cols (f0A, f0A+64)
    const int f0B = f0A + 8;          // second pair: cols (f0B, f0B+64)

    __shared__ __align__(16) float sH1[2][NROW * S];  // double-buffered
    __shared__ __align__(16) float sH2[NROW * S];
    __shared__ __align__(16) float sHR1[NROW * S];
    __shared__ __align__(16) float sHR2[NROW * S];
    __shared__ __align__(16) float sAH[NROW * S];
    __shared__ float sA[NROW * NN];
    __shared__ float sVec[9 * 128];
    __shared__ float sax[2][NROW];
    __shared__ double sredD[HID];
    __shared__ double sredE[HID];

    const float4* Lzr1 = (const float4*)(ws + WS_LZR1);
    const float4* Lh1  = (const float4*)(ws + WS_LH1);
    const float4* We2  = (const float4*)(ws + WS_WE2);
    const float4* Lzr2 = (const float4*)(ws + WS_LZR2);
    const float4* Lh2  = (const float4*)(ws + WS_LH2);

    const float4* HR1v = (const float4*)sHR1;
    const float4* HR2v = (const float4*)sHR2;
    const float4* AHv  = (const float4*)sAH;
    const float4* H2v  = (const float4*)sH2;

    for (int k = t; k < 2 * NROW * S; k += NTHREADS) ((float*)sH1)[k] = 0.0f;
    for (int k = t; k < NROW * S; k += NTHREADS) {
        sH2[k] = 0.0f; sHR1[k] = 0.0f; sHR2[k] = 0.0f; sAH[k] = 0.0f;
    }
    for (int k = t; k < NROW * NN; k += NTHREADS) sA[k] = ws[WS_A + k];
    for (int k = t; k < 9 * 128; k += NTHREADS) sVec[k] = ws[WS_VEC + k];

    __syncthreads();

    const float* xb = x + (size_t)b * (TSTEPS * NN);
    if (t < NROW) {  // sax for steps 0 and 1 (slot = s&1)
        float a0s = 0.0f, a1s = 0.0f;
        for (int j = 0; j < NN; j++) {
            a0s = fmaf(sA[t * NN + j], xb[j], a0s);
            a1s = fmaf(sA[t * NN + j], xb[NN + j], a1s);
        }
        sax[0][t] = a0s;
        sax[1][t] = a1s;
    }
    __syncthreads();

    // ---- persistent per-thread state carried across barriers ----
    float axp[RPT];                         // A: P1 -> P2
    v2f zg[RPT][2], h1c[RPT][2];            // A: P1 -> P2
    v2f ph[RPT][2], z2[RPT][2], h2c[RPT][2];// B: P4 -> P5 (crosses b2)
    double oA0 = 0.0, oA1 = 0.0, oB0 = 0.0, oB1 = 0.0;  // B output accum

    // ================= phase lambdas =================
    // P1 (A): layer-1 z,r gates for step s; reads H1 state s-1 = buf[(s+1)&1]
    auto l1_p1 = [&](int s) {
        const float* H1rd = sH1[(s + 1) & 1];
        const float4* H1c = (const float4*)H1rd;
        #pragma unroll
        for (int r = 0; r < RPT; r++) axp[r] = sax[s & 1][rb + r];
        v2f az[RPT][2], ar[RPT][2];
        {
            const v2f wz1A = {sVec[f0A],       sVec[f0A + 64]};
            const v2f wz1B = {sVec[f0B],       sVec[f0B + 64]};
            const v2f wr1A = {sVec[128 + f0A], sVec[128 + f0A + 64]};
            const v2f wr1B = {sVec[128 + f0B], sVec[128 + f0B + 64]};
            const v2f cz1A = {sVec[384 + f0A], sVec[384 + f0A + 64]};
            const v2f cz1B = {sVec[384 + f0B], sVec[384 + f0B + 64]};
            const v2f cr1A = {sVec[512 + f0A], sVec[512 + f0A + 64]};
            const v2f cr1B = {sVec[512 + f0B], sVec[512 + f0B + 64]};
            #pragma unroll
            for (int r = 0; r < RPT; r++) {
                az[r][0] = __builtin_elementwise_fma((v2f){axp[r], axp[r]}, wz1A, cz1A);
                az[r][1] = __builtin_elementwise_fma((v2f){axp[r], axp[r]}, wz1B, cz1B);
                ar[r][0] = __builtin_elementwise_fma((v2f){axp[r], axp[r]}, wr1A, cr1A);
                ar[r][1] = __builtin_elementwise_fma((v2f){axp[r], axp[r]}, wr1B, cr1B);
            }
        }
        #pragma unroll 2
        for (int c = 0; c < 32; ++c) {
            const float4 wz0A = Lzr1[c * 256 + f0A];
            const float4 wz1A = Lzr1[c * 256 + 64 + f0A];
            const float4 wr0A = Lzr1[c * 256 + 128 + f0A];
            const float4 wr1A = Lzr1[c * 256 + 192 + f0A];
            const float4 wz0B = Lzr1[c * 256 + f0B];
            const float4 wz1B = Lzr1[c * 256 + 64 + f0B];
            const float4 wr0B = Lzr1[c * 256 + 128 + f0B];
            const float4 wr1B = Lzr1[c * 256 + 192 + f0B];
            #pragma unroll
            for (int r = 0; r < RPT; r++) {
                const float4 h = H1c[(rb + r) * SV4 + c];
                pkf(az[r][0], h.x, lo2(wz0A)); pkf(az[r][0], h.y, hi2(wz0A));
                pkf(az[r][0], h.z, lo2(wz1A)); pkf(az[r][0], h.w, hi2(wz1A));
                pkf(ar[r][0], h.x, lo2(wr0A)); pkf(ar[r][0], h.y, hi2(wr0A));
                pkf(ar[r][0], h.z, lo2(wr1A)); pkf(ar[r][0], h.w, hi2(wr1A));
                pkf(az[r][1], h.x, lo2(wz0B)); pkf(az[r][1], h.y, hi2(wz0B));
                pkf(az[r][1], h.z, lo2(wz1B)); pkf(az[r][1], h.w, hi2(wz1B));
                pkf(ar[r][1], h.x, lo2(wr0B)); pkf(ar[r][1], h.y, hi2(wr0B));
                pkf(ar[r][1], h.z, lo2(wr1B)); pkf(ar[r][1], h.w, hi2(wr1B));
            }
        }
        #pragma unroll
        for (int r = 0; r < RPT; r++) {
            const int row = rb + r;
            zg[r][0].x = sigmoidf(az[r][0].x);
            zg[r][0].y = sigmoidf(az[r][0].y);
            zg[r][1].x = sigmoidf(az[r][1].x);
            zg[r][1].y = sigmoidf(az[r][1].y);
            const float rA0 = sigmoidf(ar[r][0].x);
            const float rA1 = sigmoidf(ar[r][0].y);
            const float rB0 = sigmoidf(ar[r][1].x);
            const float rB1 = sigmoidf(ar[r][1].y);
            h1c[r][0].x = H1rd[row * S + f0A];
            h1c[r][0].y = H1rd[row * S + f0A + 64];
            h1c[r][1].x = H1rd[row * S + f0B];
            h1c[r][1].y = H1rd[row * S + f0B + 64];
            sHR1[row * S + f0A]      = h1c[r][0].x * rA0;
            sHR1[row * S + f0A + 64] = h1c[r][0].y * rA1;
            sHR1[row * S + f0B]      = h1c[r][1].x * rB0;
            sHR1[row * S + f0B + 64] = h1c[r][1].y * rB1;
        }
    };

    // P2 (A): layer-1 h gate + H1 update for step s; writes buf[s&1]
    auto l1_p2 = [&](int s) {
        float* H1wr = sH1[s & 1];
        v2f ah[RPT][2];
        {
            const v2f wh1A = {sVec[256 + f0A], sVec[256 + f0A + 64]};
            const v2f wh1B = {sVec[256 + f0B], sVec[256 + f0B + 64]};
            const v2f ch1A = {sVec[640 + f0A], sVec[640 + f0A + 64]};
            const v2f ch1B = {sVec[640 + f0B], sVec[640 + f0B + 64]};
            #pragma unroll
            for (int r = 0; r < RPT; r++) {
                ah[r][0] = __builtin_elementwise_fma((v2f){axp[r], axp[r]}, wh1A, ch1A);
                ah[r][1] = __builtin_elementwise_fma((v2f){axp[r], axp[r]}, wh1B, ch1B);
            }
        }
        #pragma unroll 2
        for (int c = 0; c < 32; ++c) {
            const float4 wh0A = Lh1[c * 128 + f0A];
            const float4 wh1A = Lh1[c * 128 + 64 + f0A];
            const float4 wh0B = Lh1[c * 128 + f0B];
            const float4 wh1B = Lh1[c * 128 + 64 + f0B];
            #pragma unroll
            for (int r = 0; r < RPT; r++) {
                const float4 q = HR1v[(rb + r) * SV4 + c];
                pkf(ah[r][0], q.x, lo2(wh0A)); pkf(ah[r][0], q.y, hi2(wh0A));
                pkf(ah[r][0], q.z, lo2(wh1A)); pkf(ah[r][0], q.w, hi2(wh1A));
                pkf(ah[r][1], q.x, lo2(wh0B)); pkf(ah[r][1], q.y, hi2(wh0B));
                pkf(ah[r][1], q.z, lo2(wh1B)); pkf(ah[r][1], q.w, hi2(wh1B));
            }
        }
        #pragma unroll
        for (int r = 0; r < RPT; r++) {
            const int row = rb + r;
            const float n0 = fmaf(zg[r][0].x, h1c[r][0].x, (1.0f - zg[r][0].x) * tanhf(ah[r][0].x));
            const float n1 = fmaf(zg[r][0].y, h1c[r][0].y, (1.0f - zg[r][0].y) * tanhf(ah[r][0].y));
            const float n2 = fmaf(zg[r][1].x, h1c[r][1].x, (1.0f - zg[r][1].x) * tanhf(ah[r][1].x));
            const float n3 = fmaf(zg[r][1].y, h1c[r][1].y, (1.0f - zg[r][1].y) * tanhf(ah[r][1].y));
            H1wr[row * S + f0A]      = n0;
            H1wr[row * S + f0A + 64] = n1;
            H1wr[row * S + f0B]      = n2;
            H1wr[row * S + f0B + 64] = n3;
        }
    };

    // P3 (B): AH = A @ H1(state tt) for own rows/cols (LDS only)
    auto l2_p3 = [&](int tt) {
        const float* H1rd = sH1[tt & 1];
        v2f aa[RPT][2];
        #pragma unroll
        for (int r = 0; r < RPT; r++) { aa[r][0] = (v2f){0.0f, 0.0f}; aa[r][1] = (v2f){0.0f, 0.0f}; }
        #pragma unroll 3
        for (int j = 0; j < NN; j++) {
            const v2f hjA = {H1rd[j * S + f0A], H1rd[j * S + f0A + 64]};
            const v2f hjB = {H1rd[j * S + f0B], H1rd[j * S + f0B + 64]};
            #pragma unroll
            for (int r = 0; r < RPT; r++) {
                const float arj = sA[(rb + r) * NN + j];
                aa[r][0] = __builtin_elementwise_fma((v2f){arj, arj}, hjA, aa[r][0]);
                aa[r][1] = __builtin_elementwise_fma((v2f){arj, arj}, hjB, aa[r][1]);
            }
        }
        #pragma unroll
        for (int r = 0; r < RPT; r++) {
            const int row = rb + r;
            sAH[row * S + f0A]      = aa[r][0].x;
            sAH[row * S + f0A + 64] = aa[r][0].y;
            sAH[row * S + f0B]      = aa[r][1].x;
            sAH[row * S + f0B + 64] = aa[r][1].y;
        }
    };

    // P4 (B): layer-2 gcn + z,r gates; h-gate a-chunk partials into ph.
    // Two per-pair passes, each #pragma unroll 2 (plain SSA loads, no arrays).
    // Chains stay c-ascending with identical intra-c order -> bit-exact.
    auto l2_p4 = [&]() {
        v2f pz[RPT][2], pr[RPT][2];
        {
            const v2f cz2A = {sVec[768 + f0A],  sVec[768 + f0A + 64]};
            const v2f cz2B = {sVec[768 + f0B],  sVec[768 + f0B + 64]};
            const v2f cr2A = {sVec[896 + f0A],  sVec[896 + f0A + 64]};
            const v2f cr2B = {sVec[896 + f0B],  sVec[896 + f0B + 64]};
            const v2f ch2A = {sVec[1024 + f0A], sVec[1024 + f0A + 64]};
            const v2f ch2B = {sVec[1024 + f0B], sVec[1024 + f0B + 64]};
            #pragma unroll
            for (int r = 0; r < RPT; r++) {
                pz[r][0] = cz2A; pz[r][1] = cz2B;
                pr[r][0] = cr2A; pr[r][1] = cr2B;
                ph[r][0] = ch2A; ph[r][1] = ch2B;
            }
        }
        auto pass = [&](auto pc) {
            constexpr int P = decltype(pc)::v;
            const int f0p = P ? f0B : f0A;
            #pragma unroll 2
            for (int c = 0; c < 32; ++c) {
                const float4 wz0 = We2[c * 384 + f0p];
                const float4 wz1 = We2[c * 384 + 64 + f0p];
                const float4 wr0 = We2[c * 384 + 128 + f0p];
                const float4 wr1 = We2[c * 384 + 192 + f0p];
                const float4 wh0 = We2[c * 384 + 256 + f0p];
                const float4 wh1 = We2[c * 384 + 320 + f0p];
                const float4 lz0 = Lzr2[c * 256 + f0p];
                const float4 lz1 = Lzr2[c * 256 + 64 + f0p];
                const float4 lr0 = Lzr2[c * 256 + 128 + f0p];
                const float4 lr1 = Lzr2[c * 256 + 192 + f0p];
                #pragma unroll
                for (int r = 0; r < RPT; r++) {
                    const float4 a = AHv[(rb + r) * SV4 + c];
                    const float4 q = H2v[(rb + r) * SV4 + c];
                    // a-chunk then q-chunk per gate (round-8 order)
                    pkf(pz[r][P], a.x, lo2(wz0)); pkf(pz[r][P], a.y, hi2(wz0));
                    pkf(pz[r][P], a.z, lo2(wz1)); pkf(pz[r][P], a.w, hi2(wz1));
                    pkf(pz[r][P], q.x, lo2(lz0)); pkf(pz[r][P], q.y, hi2(lz0));
                    pkf(pz[r][P], q.z, lo2(lz1)); pkf(pz[r][P], q.w, hi2(lz1));
                    pkf(pr[r][P], a.x, lo2(wr0)); pkf(pr[r][P], a.y, hi2(wr0));
                    pkf(pr[r][P], a.z, lo2(wr1)); pkf(pr[r][P], a.w, hi2(wr1));
                    pkf(pr[r][P], q.x, lo2(lr0)); pkf(pr[r][P], q.y, hi2(lr0));
                    pkf(pr[r][P], q.z, lo2(lr1)); pkf(pr[r][P], q.w, hi2(lr1));
                    pkf(ph[r][P], a.x, lo2(wh0)); pkf(ph[r][P], a.y, hi2(wh0));
                    pkf(ph[r][P], a.z, lo2(wh1)); pkf(ph[r][P], a.w, hi2(wh1));
                }
            }
        };
        pass(ic<0>{});
        pass(ic<1>{});
        #pragma unroll
        for (int r = 0; r < RPT; r++) {
            const int row = rb + r;
            z2[r][0].x = sigmoidf(pz[r][0].x);
            z2[r][0].y = sigmoidf(pz[r][0].y);
            z2[r][1].x = sigmoidf(pz[r][1].x);
            z2[r][1].y = sigmoidf(pz[r][1].y);
            const float rA0 = sigmoidf(pr[r][0].x);
            const float rA1 = sigmoidf(pr[r][0].y);
            const float rB0 = sigmoidf(pr[r][1].x);
            const float rB1 = sigmoidf(pr[r][1].y);
            h2c[r][0].x = sH2[row * S + f0A];
            h2c[r][0].y = sH2[row * S + f0A + 64];
            h2c[r][1].x = sH2[row * S + f0B];
            h2c[r][1].y = sH2[row * S + f0B + 64];
            sHR2[row * S + f0A]      = h2c[r][0].x * rA0;
            sHR2[row * S + f0A + 64] = h2c[r][0].y * rA1;
            sHR2[row * S + f0B]      = h2c[r][1].x * rB0;
            sHR2[row * S + f0B + 64] = h2c[r][1].y * rB1;
        }
    };

    // P5 (B): layer-2 h gate finish + H2 update + output accum.
    auto l2_p5 = [&]() {
        #pragma unroll 2
        for (int c = 0; c < 32; ++c) {
            const float4 lh0A = Lh2[c * 128 + f0A];
            const float4 lh1A = Lh2[c * 128 + 64 + f0A];
            const float4 lh0B = Lh2[c * 128 + f0B];
            const float4 lh1B = Lh2[c * 128 + 64 + f0B];
            #pragma unroll
            for (int r = 0; r < RPT; r++) {
                const float4 q = HR2v[(rb + r) * SV4 + c];
                pkf(ph[r][0], q.x, lo2(lh0A)); pkf(ph[r][0], q.y, hi2(lh0A));
                pkf(ph[r][0], q.z, lo2(lh1A)); pkf(ph[r][0], q.w, hi2(lh1A));
                pkf(ph[r][1], q.x, lo2(lh0B)); pkf(ph[r][1], q.y, hi2(lh0B));
                pkf(ph[r][1], q.z, lo2(lh1B)); pkf(ph[r][1], q.w, hi2(lh1B));
            }
        }
        #pragma unroll
        for (int r = 0; r < RPT; r++) {
            const int row = rb + r;
            const float mA0 = fmaf(z2[r][0].x, h2c[r][0].x, (1.0f - z2[r][0].x) * tanhf(ph[r][0].x));
            const float mA1 = fmaf(z2[r][0].y, h2c[r][0].y, (1.0f - z2[r][0].y) * tanhf(ph[r][0].y));
            const float mB0 = fmaf(z2[r][1].x, h2c[r][1].x, (1.0f - z2[r][1].x) * tanhf(ph[r][1].x));
            const float mB1 = fmaf(z2[r][1].y, h2c[r][1].y, (1.0f - z2[r][1].y) * tanhf(ph[r][1].y));
            sH2[row * S + f0A]      = mA0;
            sH2[row * S + f0A + 64] = mA1;
            sH2[row * S + f0B]      = mB0;
            sH2[row * S + f0B + 64] = mB1;
            if (row < NN) {
                oA0 += (double)mA0; oA1 += (double)mA1;
                oB0 += (double)mB0; oB1 += (double)mB1;
            }
        }
    };

    // ======== pipeline prologue: A computes step 0 ========
    if (isA) l1_p1(0);
    __syncthreads();
    if (isA) l1_p2(0);
    __syncthreads();

    // ======== main ticks: 2 barriers each ========
    for (int k = 0; k < TSTEPS; k++) {
        // alpha
        if (isA) {
            if (k + 1 < TSTEPS) l1_p1(k + 1);
        } else {
            if (k >= 1) l2_p5();     // finish step k-1
            l2_p3(k);
        }
        __syncthreads();  // b1: publishes sHR1(k+1), sAH(k), sH2(k-1)
        // beta
        if (isA) {
            if (k + 1 < TSTEPS) l1_p2(k + 1);
            if (t < NROW && k + 2 < TSTEPS) {   // sax prefetch for step k+2
                const float* xt = xb + (size_t)(k + 2) * NN;
                float a = 0.0f;
                for (int j = 0; j < NN; j++) a = fmaf(sA[t * NN + j], xt[j], a);
                sax[(k + 2) & 1][t] = a;
            }
        } else {
            l2_p4();
        }
        __syncthreads();  // b2: publishes H1(k+1), sHR2(k), sax(k+2)
    }

    // ---------- Epilogue: finish step T-1, mean over (T, nodes), cls ----------
    if (!isA) {
        l2_p5();  // step T-1 (sHR2 published at final b2)
        double vA0 = oA0, vA1 = oA1, vB0 = oB0, vB1 = oB1;
        #pragma unroll
        for (int off = 32; off >= 8; off >>= 1) {
            vA0 += __shfl_down(vA0, off, 64);
            vA1 += __shfl_down(vA1, off, 64);
            vB0 += __shfl_down(vB0, off, 64);
            vB1 += __shfl_down(vB1, off, 64);
        }
        if (rg == 0) {   // lane p of each B wave owns 4 columns
            sredD[f0A]      = vA0;
            sredD[f0A + 64] = vA1;
            sredD[f0B]      = vB0;
            sredD[f0B + 64] = vB1;
        }
    }
    __syncthreads();
    if (t < HID) {
        sredE[t] = (sredD[t] / (double)(TSTEPS * NN)) * (double)cls_w[t];
    }
    __syncthreads();
    if (t < 64) {
        double v = sredE[t] + sredE[t + 64];
        for (int off = 32; off; off >>= 1) v += __shfl_down(v, off, 64);
        if (t == 0) out[b] = (float)(v + (double)cls_b[0]);
    }
}

extern "C" void kernel_launch(void* const* d_in, const int* in_sizes, int n_in,
                              void* d_out, int out_size, void* d_ws, size_t ws_size,
                              hipStream_t stream) {
    const float* x    = (const float*)d_in[0];
    const int*   ei   = (const int*)  d_in[1];
    const float* ew   = (const float*)d_in[2];
    const float* Wz1  = (const float*)d_in[3];
    const float* bz1  = (const float*)d_in[4];
    const float* lzw1 = (const float*)d_in[5];
    const float* lzb1 = (const float*)d_in[6];
    const float* Wr1  = (const float*)d_in[7];
    const float* br1  = (const float*)d_in[8];
    const float* lrw1 = (const float*)d_in[9];
    const float* lrb1 = (const float*)d_in[10];
    const float* Wh1  = (const float*)d_in[11];
    const float* bh1  = (const float*)d_in[12];
    const float* lhw1 = (const float*)d_in[13];
    const float* lhb1 = (const float*)d_in[14];
    const float* Wz2  = (const float*)d_in[15];
    const float* bz2  = (const float*)d_in[16];
    const float* lzw2 = (const float*)d_in[17];
    const float* lzb2 = (const float*)d_in[18];
    const float* Wr2  = (const float*)d_in[19];
    const float* br2  = (const float*)d_in[20];
    const float* lrw2 = (const float*)d_in[21];
    const float* lrb2 = (const float*)d_in[22];
    const float* Wh2  = (const float*)d_in[23];
    const float* bh2  = (const float*)d_in[24];
    const float* lhw2 = (const float*)d_in[25];
    const float* lhb2 = (const float*)d_in[26];
    const float* clsw = (const float*)d_in[27];
    const float* clsb = (const float*)d_in[28];

    float* ws   = (float*)d_ws;
    float* outp = (float*)d_out;

    build_A<<<1, 64, 0, stream>>>(ei, ew, ws + WS_A);
    pack_bot<<<32, 256, 0, stream>>>(lzw1, lrw1, (float4*)(ws + WS_LZR1), 2);
    pack_bot<<<16, 256, 0, stream>>>(lhw1, lhw1, (float4*)(ws + WS_LH1), 1);
    pack_bot<<<32, 256, 0, stream>>>(lzw2, lrw2, (float4*)(ws + WS_LZR2), 2);
    pack_bot<<<16, 256, 0, stream>>>(lhw2, lhw2, (float4*)(ws + WS_LH2), 1);
    make_weff2<<<48, 256, 0, stream>>>(Wz2, Wr2, Wh2, lzw2, lrw2, lhw2,
                                       (float4*)(ws + WS_WE2));
    make_vecs<<<5, 256, 0, stream>>>(Wz1, Wr1, Wh1, bz1, br1, bh1,
                                     lzw1, lrw1, lhw1, lzb1, lrb1, lhb1,
                                     bz2, br2, bh2, lzw2, lrw2, lhw2,
                                     lzb2, lrb2, lhb2, ws + WS_VEC);
    tgcn_main<<<64, NTHREADS, 0, stream>>>(x, ws, clsw, clsb, outp);
}

// Round 11
// 10081.920 us; speedup vs baseline: 2.2142x; 2.2142x over previous
//
#include <hip/hip_runtime.h>
#include <hip/hip_bf16.h>

// TGCN: B=64, T=500, N=21, HID=128.
// Round 18: layer-split across CUs. r7..r17 establish the single-block design
// is L1-return bound at ~25us/tick with both layer groups on one CU (2.3MB
// delivered/tick). This round: 128 blocks (A=layer1 on blockIdx<64, B=layer2
// on blockIdx>=64, pair b = blockIdx&63). A->B handoff: H1(k) (12KB) through
// a 2-slot ring in d_ws, device-coherent sc0sc1 stores/loads + relaxed agent
// atomic flags (no cache-maintenance storms). Compute phases are VERBATIM
// r16 -> bit-exact (absmax 0.0). Per-CU weight stream halves: A 0.77MB (5us),
// B 1.5MB (10us) -> B-bound ~11us/tick ~ 6ms.
// ws_size guard: if workspace < ring requirement, launch the proven r16
// single-block kernel instead (12.5ms).
// NEVER reorder per-element sums in the recurrence.

#define NN 21
#define NROW 24            // padded rows (21,22,23 zero)
#define HID 128
#define TSTEPS 500
#define EDGES 210
#define RPT 6              // rows per wave (4 waves per group)

// ws layout (float offsets)
#define WS_A     0        // NROW*NN floats (pad rows zeroed on build)
#define WS_VEC   1600     // 9*128
#define WS_LZR1  3200     // 32*256 float4
#define WS_LH1   36000    // 32*128 float4
#define WS_WE2   52400    // 32*384 float4
#define WS_LZR2  101600   // 32*256 float4
#define WS_LH2   134400   // 32*128 float4 -> ends 150784
#define WS_FLAGS 150784   // 4096 uints: fwd[b] at +b*32, back[b] at +2048+b*32
#define WS_RING  154880   // 64 batches x 2 slots x 3072 floats
#define RING_SLOT 3072    // NROW*HID
#define WS_END   (WS_RING + 64 * 2 * RING_SLOT)   // 548096 floats

#define WAVE_SYNC() asm volatile("s_waitcnt lgkmcnt(0)" ::: "memory")
#define VM_SYNC()   asm volatile("s_waitcnt vmcnt(0)" ::: "memory")

typedef float v2f __attribute__((ext_vector_type(2)));

__device__ __forceinline__ v2f lo2(float4 w) { v2f v = {w.x, w.y}; return v; }
__device__ __forceinline__ v2f hi2(float4 w) { v2f v = {w.z, w.w}; return v; }
__device__ __forceinline__ void pkf(v2f& acc, float s, v2f w) {
    v2f ss = {s, s};
    acc = __builtin_elementwise_fma(ss, w, acc);
}
__device__ __forceinline__ float sigmoidf(float v) {
    return 1.0f / (1.0f + expf(-v));
}
// device-coherent scalar store (bypasses L1/L2 dirty-sitting; lands at L3)
__device__ __forceinline__ void dc_store(float* p, float v) {
    asm volatile("global_store_dword %0, %1, off sc0 sc1" :: "v"(p), "v"(v) : "memory");
}

// ---- Prologue: build normalized adjacency A (21x21) in fp64, store fp32 ----
__global__ void build_A(const int* __restrict__ ei, const float* __restrict__ ew,
                        float* __restrict__ Aout) {
    __shared__ double deg[NN];
    __shared__ double dinv[NN];
    __shared__ double Asm[NN * NN];
    int t = threadIdx.x;
    for (int k = t; k < NN * NN; k += blockDim.x) Asm[k] = 0.0;
    if (t < NN) deg[t] = 1.0;  // self loop weight 1
    __syncthreads();
    if (t == 0) {
        for (int e = 0; e < EDGES; e++) deg[ei[EDGES + e]] += (double)ew[e];
        for (int i = 0; i < NN; i++) dinv[i] = deg[i] > 0.0 ? 1.0 / sqrt(deg[i]) : 0.0;
        for (int e = 0; e < EDGES; e++) {
            int s = ei[e], d = ei[EDGES + e];
            Asm[d * NN + s] += dinv[s] * (double)ew[e] * dinv[d];
        }
        for (int i = 0; i < NN; i++) Asm[i * NN + i] += dinv[i] * dinv[i];
    }
    __syncthreads();
    for (int k = t; k < NROW * NN; k += blockDim.x)
        Aout[k] = (k < NN * NN) ? (float)Asm[k] : 0.0f;
}

__global__ void init_flags(unsigned* f) {
    int i = blockIdx.x * blockDim.x + threadIdx.x;
    if (i < 4096) f[i] = 0u;
}

// ---- Prologue: repack bottom halves of (256,128) concat weights ----------
__global__ void pack_bot(const float* __restrict__ w0, const float* __restrict__ w1,
                         float4* __restrict__ out, int ngate) {
    int t = blockIdx.x * blockDim.x + threadIdx.x;
    int per_c = ngate * 128;
    int total = 32 * per_c;
    if (t >= total) return;
    int c = t / per_c, rem = t - c * per_c;
    int gate = rem >> 7;
    int r2 = rem & 127;
    int k2 = r2 >> 6;
    int f0 = r2 & 63;
    int k = 4 * c + 2 * k2;
    const float* src = (gate == 0) ? w0 : w1;
    float4 v;
    v.x = src[(128 + k) * 128 + f0];
    v.y = src[(128 + k) * 128 + f0 + 64];
    v.z = src[(128 + k + 1) * 128 + f0];
    v.w = src[(128 + k + 1) * 128 + f0 + 64];
    out[t] = v;
}

// ---- Prologue: Weff2_g = Wg_2 @ lgw_2_top, pair-interleaved, fp64 accum ----
__global__ void make_weff2(const float* __restrict__ Wz2, const float* __restrict__ Wr2,
                           const float* __restrict__ Wh2,
                           const float* __restrict__ lzw2, const float* __restrict__ lrw2,
                           const float* __restrict__ lhw2,
                           float4* __restrict__ out) {
    int t = blockIdx.x * blockDim.x + threadIdx.x;
    if (t >= 32 * 384) return;
    int c = t / 384, rem = t - c * 384;
    int g = rem >> 7;
    int r2 = rem & 127;
    int k2 = r2 >> 6;
    int f0 = r2 & 63;
    int k = 4 * c + 2 * k2;
    const float* W = (g == 0) ? Wz2 : (g == 1) ? Wr2 : Wh2;
    const float* L = (g == 0) ? lzw2 : (g == 1) ? lrw2 : lhw2;
    double a0 = 0, a1 = 0, a2 = 0, a3 = 0;
    for (int m = 0; m < 128; m++) {
        double w0 = (double)W[k * 128 + m];
        double w1 = (double)W[(k + 1) * 128 + m];
        a0 += w0 * (double)L[m * 128 + f0];
        a1 += w0 * (double)L[m * 128 + f0 + 64];
        a2 += w1 * (double)L[m * 128 + f0];
        a3 += w1 * (double)L[m * 128 + f0 + 64];
    }
    out[t] = make_float4((float)a0, (float)a1, (float)a2, (float)a3);
}

// ---- Prologue: layer-1 effective row vectors + all bias consts (fp64) ----
__global__ void make_vecs(const float* __restrict__ Wz1, const float* __restrict__ Wr1,
                          const float* __restrict__ Wh1,
                          const float* __restrict__ bz1, const float* __restrict__ br1,
                          const float* __restrict__ bh1,
                          const float* __restrict__ lzw1, const float* __restrict__ lrw1,
                          const float* __restrict__ lhw1,
                          const float* __restrict__ lzb1, const float* __restrict__ lrb1,
                          const float* __restrict__ lhb1,
                          const float* __restrict__ bz2, const float* __restrict__ br2,
                          const float* __restrict__ bh2,
                          const float* __restrict__ lzw2, const float* __restrict__ lrw2,
                          const float* __restrict__ lhw2,
                          const float* __restrict__ lzb2, const float* __restrict__ lrb2,
                          const float* __restrict__ lhb2,
                          float* __restrict__ out) {
    int t = blockIdx.x * blockDim.x + threadIdx.x;
    if (t >= 9 * 128) return;
    int v = t >> 7, f = t & 127;
    double acc = 0.0;
    if (v < 3) {
        const float* W = (v == 0) ? Wz1 : (v == 1) ? Wr1 : Wh1;
        const float* L = (v == 0) ? lzw1 : (v == 1) ? lrw1 : lhw1;
        for (int m = 0; m < 128; m++) acc += (double)W[m] * (double)L[m * 128 + f];
    } else if (v < 6) {
        int g = v - 3;
        const float* bb = (g == 0) ? bz1 : (g == 1) ? br1 : bh1;
        const float* L  = (g == 0) ? lzw1 : (g == 1) ? lrw1 : lhw1;
        const float* lb = (g == 0) ? lzb1 : (g == 1) ? lrb1 : lhb1;
        for (int m = 0; m < 128; m++) acc += (double)bb[m] * (double)L[m * 128 + f];
        acc += (double)lb[f];
    } else {
        int g = v - 6;
        const float* bb = (g == 0) ? bz2 : (g == 1) ? br2 : bh2;
        const float* L  = (g == 0) ? lzw2 : (g == 1) ? lrw2 : lhw2;
        const float* lb = (g == 0) ? lzb2 : (g == 1) ? lrb2 : lhb2;
        for (int m = 0; m < 128; m++) acc += (double)bb[m] * (double)L[m * 128 + f];
        acc += (double)lb[f];
    }
    out[t] = (float)acc;
}

// ================= split kernel: 128 blocks x 256 threads =================
__global__ __launch_bounds__(256, 1) void tgcn_split(
    const float* __restrict__ x, float* __restrict__ ws,
    const float* __restrict__ cls_w, const float* __restrict__ cls_b,
    float* __restrict__ out)
{
    const int bid = blockIdx.x;
    const bool roleA = (bid < 64);
    const int b  = bid & 63;
    const int t  = threadIdx.x;
    const int f0 = t & 63;
    const int f1 = f0 + 64;
    const int gw = __builtin_amdgcn_readfirstlane(t >> 6);  // 0..3
    const int iA = gw * RPT;
    const int nreal = (iA + RPT <= NN) ? RPT : (NN - iA);

    unsigned* fwdp  = (unsigned*)(ws + WS_FLAGS) + b * 32;
    unsigned* backp = (unsigned*)(ws + WS_FLAGS) + 2048 + b * 32;
    float* ringB = ws + WS_RING + (size_t)b * (2 * RING_SLOT);

    // ---- LDS (A-role and B-role sets; both fit) ----
    __shared__ __align__(16) float sH1[2][NROW * HID];  // A: double-buffered state
    __shared__ __align__(16) float sHR1[NROW * HID];    // A
    __shared__ __align__(16) float sH1B[NROW * HID];    // B: staged H1(k)
    __shared__ __align__(16) float sH2[NROW * HID];     // B
    __shared__ __align__(16) float sHR2[NROW * HID];    // B
    __shared__ __align__(16) float sAH[NROW * HID];     // B
    __shared__ float sA[NROW * NN];
    __shared__ float sax[2][NROW];                      // A
    __shared__ double sred[4][HID];                     // B

    const float*  vecs = ws + WS_VEC;
    const float4* Lzr1 = (const float4*)(ws + WS_LZR1);
    const float4* Lh1  = (const float4*)(ws + WS_LH1);
    const float4* We2  = (const float4*)(ws + WS_WE2);
    const float4* Lzr2 = (const float4*)(ws + WS_LZR2);
    const float4* Lh2  = (const float4*)(ws + WS_LH2);

    const float4* HR1v = (const float4*)sHR1;
    const float4* HR2v = (const float4*)sHR2;
    const float4* AHv  = (const float4*)sAH;
    const float4* H2v  = (const float4*)sH2;

    for (int k = t; k < 2 * NROW * HID; k += 256) ((float*)sH1)[k] = 0.0f;
    for (int k = t; k < NROW * HID; k += 256) {
        sH2[k] = 0.0f; sHR1[k] = 0.0f; sHR2[k] = 0.0f; sAH[k] = 0.0f; sH1B[k] = 0.0f;
    }
    for (int k = t; k < NROW * NN; k += 256) sA[k] = ws[WS_A + k];

    // per-column-pair constants (registers; same as r16)
    const v2f wz1v = {vecs[f0],        vecs[f1]};
    const v2f wr1v = {vecs[128 + f0],  vecs[128 + f1]};
    const v2f wh1v = {vecs[256 + f0],  vecs[256 + f1]};
    const v2f cz1v = {vecs[384 + f0],  vecs[384 + f1]};
    const v2f cr1v = {vecs[512 + f0],  vecs[512 + f1]};
    const v2f ch1v = {vecs[640 + f0],  vecs[640 + f1]};
    const v2f cz2v = {vecs[768 + f0],  vecs[768 + f1]};
    const v2f cr2v = {vecs[896 + f0],  vecs[896 + f1]};
    const v2f ch2v = {vecs[1024 + f0], vecs[1024 + f1]};

    __syncthreads();

    if (roleA) {
        // =================== A: layer-1 producer ===================
        const float* xb = x + (size_t)b * (TSTEPS * NN);
        if (t < NROW) {  // sax for steps 0 and 1
            float a0s = 0.0f, a1s = 0.0f;
            for (int j = 0; j < NN; j++) {
                a0s = fmaf(sA[t * NN + j], xb[j], a0s);
                a1s = fmaf(sA[t * NN + j], xb[NN + j], a1s);
            }
            sax[0][t] = a0s;
            sax[1][t] = a1s;
        }
        __syncthreads();

        for (int s = 0; s < TSTEPS; s++) {
            if (t == 0 && s >= 2) {   // ring back-pressure: slot s&1 free?
                while (__hip_atomic_load(backp, __ATOMIC_RELAXED,
                                         __HIP_MEMORY_SCOPE_AGENT) < (unsigned)(s - 1))
                    __builtin_amdgcn_s_sleep(2);
            }
            __syncthreads();

            // ---- layer1(s): P1 + WAVE_SYNC + P2 (verbatim r16) + ring mirror ----
            {
                const float* H1rd = sH1[(s + 1) & 1];
                float*       H1wr = sH1[s & 1];
                const float4* H1c = (const float4*)H1rd;
                float* g = ringB + (s & 1) * RING_SLOT;
                float axp[RPT];
                #pragma unroll
                for (int r = 0; r < RPT; r++) axp[r] = sax[s & 1][iA + r];
                v2f az[RPT], ar[RPT];
                #pragma unroll
                for (int r = 0; r < RPT; r++) {
                    az[r] = __builtin_elementwise_fma((v2f){axp[r], axp[r]}, wz1v, cz1v);
                    ar[r] = __builtin_elementwise_fma((v2f){axp[r], axp[r]}, wr1v, cr1v);
                }
                #pragma unroll 2
                for (int c = 0; c < 32; ++c) {
                    const float4 wz0 = Lzr1[c * 256 + f0];
                    const float4 wz1 = Lzr1[c * 256 + 64 + f0];
                    const float4 wr0 = Lzr1[c * 256 + 128 + f0];
                    const float4 wr1 = Lzr1[c * 256 + 192 + f0];
                    #pragma unroll
                    for (int r = 0; r < RPT; r++) {
                        const float4 h = H1c[(iA + r) * 32 + c];
                        pkf(az[r], h.x, lo2(wz0)); pkf(az[r], h.y, hi2(wz0));
                        pkf(az[r], h.z, lo2(wz1)); pkf(az[r], h.w, hi2(wz1));
                        pkf(ar[r], h.x, lo2(wr0)); pkf(ar[r], h.y, hi2(wr0));
                        pkf(ar[r], h.z, lo2(wr1)); pkf(ar[r], h.w, hi2(wr1));
                    }
                }
                v2f zg[RPT], h1c[RPT];
                #pragma unroll
                for (int r = 0; r < RPT; r++) {
                    zg[r].x = sigmoidf(az[r].x);
                    zg[r].y = sigmoidf(az[r].y);
                    const float r0 = sigmoidf(ar[r].x);
                    const float r1 = sigmoidf(ar[r].y);
                    h1c[r].x = H1rd[(iA + r) * HID + f0];
                    h1c[r].y = H1rd[(iA + r) * HID + f1];
                    sHR1[(iA + r) * HID + f0] = h1c[r].x * r0;
                    sHR1[(iA + r) * HID + f1] = h1c[r].y * r1;
                }
                WAVE_SYNC();
                v2f ah[RPT];
                #pragma unroll
                for (int r = 0; r < RPT; r++)
                    ah[r] = __builtin_elementwise_fma((v2f){axp[r], axp[r]}, wh1v, ch1v);
                #pragma unroll 2
                for (int c = 0; c < 32; ++c) {
                    const float4 wh0 = Lh1[c * 128 + f0];
                    const float4 wh1 = Lh1[c * 128 + 64 + f0];
                    #pragma unroll
                    for (int r = 0; r < RPT; r++) {
                        const float4 q = HR1v[(iA + r) * 32 + c];
                        pkf(ah[r], q.x, lo2(wh0)); pkf(ah[r], q.y, hi2(wh0));
                        pkf(ah[r], q.z, lo2(wh1)); pkf(ah[r], q.w, hi2(wh1));
                    }
                }
                #pragma unroll
                for (int r = 0; r < RPT; r++) {
                    const int row = iA + r;
                    const float n0 = fmaf(zg[r].x, h1c[r].x, (1.0f - zg[r].x) * tanhf(ah[r].x));
                    const float n1 = fmaf(zg[r].y, h1c[r].y, (1.0f - zg[r].y) * tanhf(ah[r].y));
                    H1wr[row * HID + f0] = n0;
                    H1wr[row * HID + f1] = n1;
                    dc_store(g + row * HID + f0, n0);   // device-coherent mirror
                    dc_store(g + row * HID + f1, n1);
                }
            }
            // sax prefetch for step s+2 (wave 0)
            if (t < NROW && s + 2 < TSTEPS) {
                const float* xt = xb + (size_t)(s + 2) * NN;
                float a = 0.0f;
                for (int j = 0; j < NN; j++) a = fmaf(sA[t * NN + j], xt[j], a);
                sax[(s + 2) & 1][t] = a;
            }
            VM_SYNC();         // all mirror stores device-visible
            __syncthreads();
            if (t == 0)
                __hip_atomic_store(fwdp, (unsigned)(s + 1), __ATOMIC_RELAXED,
                                   __HIP_MEMORY_SCOPE_AGENT);
        }
        return;
    }

    // =================== B: layer-2 consumer ===================
    double oacc0 = 0.0, oacc1 = 0.0;
    v2f ph[RPT], z2[RPT], h2c[RPT];   // carried P4 -> P5

    auto l2_p5 = [&]() {
        #pragma unroll 2
        for (int c = 0; c < 32; ++c) {
            const float4 lh0 = Lh2[c * 128 + f0];
            const float4 lh1 = Lh2[c * 128 + 64 + f0];
            #pragma unroll
            for (int r = 0; r < RPT; r++) {
                const float4 q = HR2v[(iA + r) * 32 + c];
                pkf(ph[r], q.x, lo2(lh0)); pkf(ph[r], q.y, hi2(lh0));
                pkf(ph[r], q.z, lo2(lh1)); pkf(ph[r], q.w, hi2(lh1));
            }
        }
        #pragma unroll
        for (int r = 0; r < RPT; r++) {
            const float m0 = fmaf(z2[r].x, h2c[r].x, (1.0f - z2[r].x) * tanhf(ph[r].x));
            const float m1 = fmaf(z2[r].y, h2c[r].y, (1.0f - z2[r].y) * tanhf(ph[r].y));
            sH2[(iA + r) * HID + f0] = m0;
            sH2[(iA + r) * HID + f1] = m1;
            if (r < nreal) {
                oacc0 += (double)m0;
                oacc1 += (double)m1;
            }
        }
    };

    for (int k = 0; k < TSTEPS; k++) {
        if (k >= 1) l2_p5();          // finish step k-1 (wave-private state)
        if (t == 0) {
            while (__hip_atomic_load(fwdp, __ATOMIC_RELAXED,
                                     __HIP_MEMORY_SCOPE_AGENT) < (unsigned)(k + 1))
                __builtin_amdgcn_s_sleep(2);
        }
        __syncthreads();
        // stage H1(k): 768 float4, 3 per thread, device-coherent loads
        {
            const float4* gs = (const float4*)(ringB + (k & 1) * RING_SLOT);
            const float4* p0 = gs + t;
            const float4* p1 = gs + t + 256;
            const float4* p2 = gs + t + 512;
            float4 v0, v1, v2;
            asm volatile(
                "global_load_dwordx4 %0, %3, off sc0 sc1\n\t"
                "global_load_dwordx4 %1, %4, off sc0 sc1\n\t"
                "global_load_dwordx4 %2, %5, off sc0 sc1\n\t"
                "s_waitcnt vmcnt(0)"
                : "=v"(v0), "=v"(v1), "=v"(v2)
                : "v"(p0), "v"(p1), "v"(p2)
                : "memory");
            float4* sB = (float4*)sH1B;
            sB[t] = v0; sB[t + 256] = v1; sB[t + 512] = v2;
        }
        WAVE_SYNC();
        __syncthreads();              // staged H1 visible to all waves
        if (t == 0)
            __hip_atomic_store(backp, (unsigned)(k + 1), __ATOMIC_RELAXED,
                               __HIP_MEMORY_SCOPE_AGENT);
        // ---- P3: AH = A @ H1(k) ----
        {
            v2f aa[RPT];
            #pragma unroll
            for (int r = 0; r < RPT; r++) aa[r] = (v2f){0.0f, 0.0f};
            #pragma unroll 3
            for (int j = 0; j < NN; j++) {
                const v2f hj = {sH1B[j * HID + f0], sH1B[j * HID + f1]};
                #pragma unroll
                for (int r = 0; r < RPT; r++) {
                    const float arj = sA[(iA + r) * NN + j];
                    aa[r] = __builtin_elementwise_fma((v2f){arj, arj}, hj, aa[r]);
                }
            }
            #pragma unroll
            for (int r = 0; r < RPT; r++) {
                sAH[(iA + r) * HID + f0] = aa[r].x;
                sAH[(iA + r) * HID + f1] = aa[r].y;
            }
        }
        WAVE_SYNC();
        // ---- P4: layer-2 gcn + z,r gates (verbatim r16) ----
        {
            v2f pz[RPT], pr[RPT];
            #pragma unroll
            for (int r = 0; r < RPT; r++) { pz[r] = cz2v; pr[r] = cr2v; ph[r] = ch2v; }
            for (int c = 0; c < 32; ++c) {
                const float4 wz0 = We2[c * 384 + f0];
                const float4 wz1 = We2[c * 384 + 64 + f0];
                const float4 wr0 = We2[c * 384 + 128 + f0];
                const float4 wr1 = We2[c * 384 + 192 + f0];
                const float4 wh0 = We2[c * 384 + 256 + f0];
                const float4 wh1 = We2[c * 384 + 320 + f0];
                const float4 lz0 = Lzr2[c * 256 + f0];
                const float4 lz1 = Lzr2[c * 256 + 64 + f0];
                const float4 lr0 = Lzr2[c * 256 + 128 + f0];
                const float4 lr1 = Lzr2[c * 256 + 192 + f0];
                #pragma unroll
                for (int r = 0; r < RPT; r++) {
                    const float4 a = AHv[(iA + r) * 32 + c];
                    const float4 q = H2v[(iA + r) * 32 + c];
                    pkf(pz[r], a.x, lo2(wz0)); pkf(pz[r], a.y, hi2(wz0));
                    pkf(pz[r], a.z, lo2(wz1)); pkf(pz[r], a.w, hi2(wz1));
                    pkf(pz[r], q.x, lo2(lz0)); pkf(pz[r], q.y, hi2(lz0));
                    pkf(pz[r], q.z, lo2(lz1)); pkf(pz[r], q.w, hi2(lz1));
                    pkf(pr[r], a.x, lo2(wr0)); pkf(pr[r], a.y, hi2(wr0));
                    pkf(pr[r], a.z, lo2(wr1)); pkf(pr[r], a.w, hi2(wr1));
                    pkf(pr[r], q.x, lo2(lr0)); pkf(pr[r], q.y, hi2(lr0));
                    pkf(pr[r], q.z, lo2(lr1)); pkf(pr[r], q.w, hi2(lr1));
                    pkf(ph[r], a.x, lo2(wh0)); pkf(ph[r], a.y, hi2(wh0));
                    pkf(ph[r], a.z, lo2(wh1)); pkf(ph[r], a.w, hi2(wh1));
                }
            }
            #pragma unroll
            for (int r = 0; r < RPT; r++) {
                z2[r].x = sigmoidf(pz[r].x);
                z2[r].y = sigmoidf(pz[r].y);
                const float r20 = sigmoidf(pr[r].x);
                const float r21 = sigmoidf(pr[r].y);
                h2c[r].x = sH2[(iA + r) * HID + f0];
                h2c[r].y = sH2[(iA + r) * HID + f1];
                sHR2[(iA + r) * HID + f0] = h2c[r].x * r20;
                sHR2[(iA + r) * HID + f1] = h2c[r].y * r21;
            }
        }
        WAVE_SYNC();
    }

    // ---------- Epilogue: finish step T-1, mean, cls ----------
    l2_p5();
    sred[gw][f0] = oacc0;
    sred[gw][f1] = oacc1;
    __syncthreads();
    if (t < HID) {
        double s = 0.0;
        for (int gg = 0; gg < 4; gg++) s += sred[gg][t];
        sred[0][t] = (s / (double)(TSTEPS * NN)) * (double)cls_w[t];
    }
    __syncthreads();
    if (t < 64) {
        double v = ((double*)sred)[t] + ((double*)sred)[t + 64];
        for (int off = 32; off; off >>= 1) v += __shfl_down(v, off, 64);
        if (t == 0) out[b] = (float)(v + (double)cls_b[0]);
    }
}

// ================= fallback: r16 single-block kernel (proven 12.5ms) ========
#define NTHREADS 512
__global__ __launch_bounds__(NTHREADS, 1) void tgcn_main(
    const float* __restrict__ x, const float* __restrict__ ws,
    const float* __restrict__ cls_w, const float* __restrict__ cls_b,
    float* __restrict__ out)
{
    const int b  = blockIdx.x;
    const int t  = threadIdx.x;
    const bool isA = (t < 256);
    const int lt = t & 255;
    const int f0 = lt & 63;
    const int f1 = f0 + 64;
    const int gw = __builtin_amdgcn_readfirstlane(lt >> 6);
    const int iA = gw * RPT;
    const int nreal = (iA + RPT <= NN) ? RPT : (NN - iA);

    __shared__ __align__(16) float sH1[2][NROW * HID];
    __shared__ __align__(16) float sH2[NROW * HID];
    __shared__ __align__(16) float sHR1[NROW * HID];
    __shared__ __align__(16) float sHR2[NROW * HID];
    __shared__ __align__(16) float sAH[NROW * HID];
    __shared__ float sA[NROW * NN];
    __shared__ float sax[2][NROW];
    __shared__ double sred[4][HID];

    const float*  vecs = ws + WS_VEC;
    const float4* Lzr1 = (const float4*)(ws + WS_LZR1);
    const float4* Lh1  = (const float4*)(ws + WS_LH1);
    const float4* We2  = (const float4*)(ws + WS_WE2);
    const float4* Lzr2 = (const float4*)(ws + WS_LZR2);
    const float4* Lh2  = (const float4*)(ws + WS_LH2);

    const float4* H2v  = (const float4*)sH2;
    const float4* HR1v = (const float4*)sHR1;
    const float4* HR2v = (const float4*)sHR2;
    const float4* AHv  = (const float4*)sAH;

    for (int k = t; k < 2 * NROW * HID; k += NTHREADS) ((float*)sH1)[k] = 0.0f;
    for (int k = t; k < NROW * HID; k += NTHREADS) sH2[k] = 0.0f;
    for (int k = t; k < NROW * NN; k += NTHREADS) sA[k] = ws[WS_A + k];

    const v2f wz1v = {vecs[f0],        vecs[f1]};
    const v2f wr1v = {vecs[128 + f0],  vecs[128 + f1]};
    const v2f wh1v = {vecs[256 + f0],  vecs[256 + f1]};
    const v2f cz1v = {vecs[384 + f0],  vecs[384 + f1]};
    const v2f cr1v = {vecs[512 + f0],  vecs[512 + f1]};
    const v2f ch1v = {vecs[640 + f0],  vecs[640 + f1]};
    const v2f cz2v = {vecs[768 + f0],  vecs[768 + f1]};
    const v2f cr2v = {vecs[896 + f0],  vecs[896 + f1]};
    const v2f ch2v = {vecs[1024 + f0], vecs[1024 + f1]};

    __syncthreads();

    const float* xb = x + (size_t)b * (TSTEPS * NN);
    if (t < NROW) {
        float a0s = 0.0f, a1s = 0.0f;
        for (int j = 0; j < NN; j++) {
            a0s = fmaf(sA[t * NN + j], xb[j], a0s);
            a1s = fmaf(sA[t * NN + j], xb[NN + j], a1s);
        }
        sax[0][t] = a0s;
        sax[1][t] = a1s;
    }
    __syncthreads();

    double oacc0 = 0.0, oacc1 = 0.0;

    auto layer1 = [&](int s) {
        const float* H1rd = sH1[(s + 1) & 1];
        float*       H1wr = sH1[s & 1];
        const float4* H1c = (const float4*)H1rd;
        float axp[RPT];
        #pragma unroll
        for (int r = 0; r < RPT; r++) axp[r] = sax[s & 1][iA + r];
        v2f az[RPT], ar[RPT];
        #pragma unroll
        for (int r = 0; r < RPT; r++) {
            az[r] = __builtin_elementwise_fma((v2f){axp[r], axp[r]}, wz1v, cz1v);
            ar[r] = __builtin_elementwise_fma((v2f){axp[r], axp[r]}, wr1v, cr1v);
        }
        #pragma unroll 2
        for (int c = 0; c < 32; ++c) {
            const float4 wz0 = Lzr1[c * 256 + f0];
            const float4 wz1 = Lzr1[c * 256 + 64 + f0];
            const float4 wr0 = Lzr1[c * 256 + 128 + f0];
            const float4 wr1 = Lzr1[c * 256 + 192 + f0];
            #pragma unroll
            for (int r = 0; r < RPT; r++) {
                const float4 h = H1c[(iA + r) * 32 + c];
                pkf(az[r], h.x, lo2(wz0)); pkf(az[r], h.y, hi2(wz0));
                pkf(az[r], h.z, lo2(wz1)); pkf(az[r], h.w, hi2(wz1));
                pkf(ar[r], h.x, lo2(wr0)); pkf(ar[r], h.y, hi2(wr0));
                pkf(ar[r], h.z, lo2(wr1)); pkf(ar[r], h.w, hi2(wr1));
            }
        }
        v2f zg[RPT], h1c[RPT];
        #pragma unroll
        for (int r = 0; r < RPT; r++) {
            zg[r].x = sigmoidf(az[r].x);
            zg[r].y = sigmoidf(az[r].y);
            const float r0 = sigmoidf(ar[r].x);
            const float r1 = sigmoidf(ar[r].y);
            h1c[r].x = H1rd[(iA + r) * HID + f0];
            h1c[r].y = H1rd[(iA + r) * HID + f1];
            sHR1[(iA + r) * HID + f0] = h1c[r].x * r0;
            sHR1[(iA + r) * HID + f1] = h1c[r].y * r1;
        }
        WAVE_SYNC();
        v2f ah[RPT];
        #pragma unroll
        for (int r = 0; r < RPT; r++)
            ah[r] = __builtin_elementwise_fma((v2f){axp[r], axp[r]}, wh1v, ch1v);
        #pragma unroll 2
        for (int c = 0; c < 32; ++c) {
            const float4 wh0 = Lh1[c * 128 + f0];
            const float4 wh1 = Lh1[c * 128 + 64 + f0];
            #pragma unroll
            for (int r = 0; r < RPT; r++) {
                const float4 q = HR1v[(iA + r) * 32 + c];
                pkf(ah[r], q.x, lo2(wh0)); pkf(ah[r], q.y, hi2(wh0));
                pkf(ah[r], q.z, lo2(wh1)); pkf(ah[r], q.w, hi2(wh1));
            }
        }
        #pragma unroll
        for (int r = 0; r < RPT; r++) {
            const float n0 = fmaf(zg[r].x, h1c[r].x, (1.0f - zg[r].x) * tanhf(ah[r].x));
            const float n1 = fmaf(zg[r].y, h1c[r].y, (1.0f - zg[r].y) * tanhf(ah[r].y));
            H1wr[(iA + r) * HID + f0] = n0;
            H1wr[(iA + r) * HID + f1] = n1;
        }
    };

    if (isA) layer1(0);
    __syncthreads();

    for (int k = 0; k < TSTEPS; k++) {
        if (isA) {
            if (k + 1 < TSTEPS) {
                layer1(k + 1);
                if (t < NROW && k + 2 < TSTEPS) {
                    const float* xt = xb + (size_t)(k + 2) * NN;
                    float a = 0.0f;
                    for (int j = 0; j < NN; j++) a = fmaf(sA[t * NN + j], xt[j], a);
                    sax[(k + 2) & 1][t] = a;
                }
            }
        } else {
            const float* H1rd = sH1[k & 1];
            v2f aa[RPT];
            #pragma unroll
            for (int r = 0; r < RPT; r++) aa[r] = (v2f){0.0f, 0.0f};
            #pragma unroll 3
            for (int j = 0; j < NN; j++) {
                const v2f hj = {H1rd[j * HID + f0], H1rd[j * HID + f1]};
                #pragma unroll
                for (int r = 0; r < RPT; r++) {
                    const float arj = sA[(iA + r) * NN + j];
                    aa[r] = __builtin_elementwise_fma((v2f){arj, arj}, hj, aa[r]);
                }
            }
            #pragma unroll
            for (int r = 0; r < RPT; r++) {
                sAH[(iA + r) * HID + f0] = aa[r].x;
                sAH[(iA + r) * HID + f1] = aa[r].y;
            }
            WAVE_SYNC();
            v2f pz[RPT], pr[RPT], ph[RPT];
            #pragma unroll
            for (int r = 0; r < RPT; r++) { pz[r] = cz2v; pr[r] = cr2v; ph[r] = ch2v; }
            for (int c = 0; c < 32; ++c) {
                const float4 wz0 = We2[c * 384 + f0];
                const float4 wz1 = We2[c * 384 + 64 + f0];
                const float4 wr0 = We2[c * 384 + 128 + f0];
                const float4 wr1 = We2[c * 384 + 192 + f0];
                const float4 wh0 = We2[c * 384 + 256 + f0];
                const float4 wh1 = We2[c * 384 + 320 + f0];
                const float4 lz0 = Lzr2[c * 256 + f0];
                const float4 lz1 = Lzr2[c * 256 + 64 + f0];
                const float4 lr0 = Lzr2[c * 256 + 128 + f0];
                const float4 lr1 = Lzr2[c * 256 + 192 + f0];
                #pragma unroll
                for (int r = 0; r < RPT; r++) {
                    const float4 a = AHv[(iA + r) * 32 + c];
                    const float4 q = H2v[(iA + r) * 32 + c];
                    pkf(pz[r], a.x, lo2(wz0)); pkf(pz[r], a.y, hi2(wz0));
                    pkf(pz[r], a.z, lo2(wz1)); pkf(pz[r], a.w, hi2(wz1));
                    pkf(pz[r], q.x, lo2(lz0)); pkf(pz[r], q.y, hi2(lz0));
                    pkf(pz[r], q.z, lo2(lz1)); pkf(pz[r], q.w, hi2(lz1));
                    pkf(pr[r], a.x, lo2(wr0)); pkf(pr[r], a.y, hi2(wr0));
                    pkf(pr[r], a.z, lo2(wr1)); pkf(pr[r], a.w, hi2(wr1));
                    pkf(pr[r], q.x, lo2(lr0)); pkf(pr[r], q.y, hi2(lr0));
                    pkf(pr[r], q.z, lo2(lr1)); pkf(pr[r], q.w, hi2(lr1));
                    pkf(ph[r], a.x, lo2(wh0)); pkf(ph[r], a.y, hi2(wh0));
                    pkf(ph[r], a.z, lo2(wh1)); pkf(ph[r], a.w, hi2(wh1));
                }
            }
            v2f z2[RPT], h2c[RPT];
            #pragma unroll
            for (int r = 0; r < RPT; r++) {
                z2[r].x = sigmoidf(pz[r].x);
                z2[r].y = sigmoidf(pz[r].y);
                const float r20 = sigmoidf(pr[r].x);
                const float r21 = sigmoidf(pr[r].y);
                h2c[r].x = sH2[(iA + r) * HID + f0];
                h2c[r].y = sH2[(iA + r) * HID + f1];
                sHR2[(iA + r) * HID + f0] = h2c[r].x * r20;
                sHR2[(iA + r) * HID + f1] = h2c[r].y * r21;
            }
            WAVE_SYNC();
            #pragma unroll 2
            for (int c = 0; c < 32; ++c) {
                const float4 lh0 = Lh2[c * 128 + f0];
                const float4 lh1 = Lh2[c * 128 + 64 + f0];
                #pragma unroll
                for (int r = 0; r < RPT; r++) {
                    const float4 q = HR2v[(iA + r) * 32 + c];
                    pkf(ph[r], q.x, lo2(lh0)); pkf(ph[r], q.y, hi2(lh0));
                    pkf(ph[r], q.z, lo2(lh1)); pkf(ph[r], q.w, hi2(lh1));
                }
            }
            #pragma unroll
            for (int r = 0; r < RPT; r++) {
                const float m0 = fmaf(z2[r].x, h2c[r].x, (1.0f - z2[r].x) * tanhf(ph[r].x));
                const float m1 = fmaf(z2[r].y, h2c[r].y, (1.0f - z2[r].y) * tanhf(ph[r].y));
                sH2[(iA + r) * HID + f0] = m0;
                sH2[(iA + r) * HID + f1] = m1;
                if (r < nreal) {
                    oacc0 += (double)m0;
                    oacc1 += (double)m1;
                }
            }
        }
        __syncthreads();
    }

    if (!isA) {
        sred[gw][f0] = oacc0;
        sred[gw][f1] = oacc1;
    }
    __syncthreads();
    if (t < HID) {
        double s = 0.0;
        for (int gg = 0; gg < 4; gg++) s += sred[gg][t];
        sred[0][t] = (s / (double)(TSTEPS * NN)) * (double)cls_w[t];
    }
    __syncthreads();
    if (t < 64) {
        double v = ((double*)sred)[t] + ((double*)sred)[t + 64];
        for (int off = 32; off; off >>= 1) v += __shfl_down(v, off, 64);
        if (t == 0) out[b] = (float)(v + (double)cls_b[0]);
    }
}

extern "C" void kernel_launch(void* const* d_in, const int* in_sizes, int n_in,
                              void* d_out, int out_size, void* d_ws, size_t ws_size,
                              hipStream_t stream) {
    const float* x    = (const float*)d_in[0];
    const int*   ei   = (const int*)  d_in[1];
    const float* ew   = (const float*)d_in[2];
    const float* Wz1  = (const float*)d_in[3];
    const float* bz1  = (const float*)d_in[4];
    const float* lzw1 = (const float*)d_in[5];
    const float* lzb1 = (const float*)d_in[6];
    const float* Wr1  = (const float*)d_in[7];
    const float* br1  = (const float*)d_in[8];
    const float* lrw1 = (const float*)d_in[9];
    const float* lrb1 = (const float*)d_in[10];
    const float* Wh1  = (const float*)d_in[11];
    const float* bh1  = (const float*)d_in[12];
    const float* lhw1 = (const float*)d_in[13];
    const float* lhb1 = (const float*)d_in[14];
    const float* Wz2  = (const float*)d_in[15];
    const float* bz2  = (const float*)d_in[16];
    const float* lzw2 = (const float*)d_in[17];
    const float* lzb2 = (const float*)d_in[18];
    const float* Wr2  = (const float*)d_in[19];
    const float* br2  = (const float*)d_in[20];
    const float* lrw2 = (const float*)d_in[21];
    const float* lrb2 = (const float*)d_in[22];
    const float* Wh2  = (const float*)d_in[23];
    const float* bh2  = (const float*)d_in[24];
    const float* lhw2 = (const float*)d_in[25];
    const float* lhb2 = (const float*)d_in[26];
    const float* clsw = (const float*)d_in[27];
    const float* clsb = (const float*)d_in[28];

    float* ws   = (float*)d_ws;
    float* outp = (float*)d_out;

    build_A<<<1, 64, 0, stream>>>(ei, ew, ws + WS_A);
    pack_bot<<<32, 256, 0, stream>>>(lzw1, lrw1, (float4*)(ws + WS_LZR1), 2);
    pack_bot<<<16, 256, 0, stream>>>(lhw1, lhw1, (float4*)(ws + WS_LH1), 1);
    pack_bot<<<32, 256, 0, stream>>>(lzw2, lrw2, (float4*)(ws + WS_LZR2), 2);
    pack_bot<<<16, 256, 0, stream>>>(lhw2, lhw2, (float4*)(ws + WS_LH2), 1);
    make_weff2<<<48, 256, 0, stream>>>(Wz2, Wr2, Wh2, lzw2, lrw2, lhw2,
                                       (float4*)(ws + WS_WE2));
    make_vecs<<<5, 256, 0, stream>>>(Wz1, Wr1, Wh1, bz1, br1, bh1,
                                     lzw1, lrw1, lhw1, lzb1, lrb1, lhb1,
                                     bz2, br2, bh2, lzw2, lrw2, lhw2,
                                     lzb2, lrb2, lhb2, ws + WS_VEC);

    const size_t need = (size_t)WS_END * sizeof(float);
    if (ws_size >= need) {
        init_flags<<<16, 256, 0, stream>>>((unsigned*)(ws + WS_FLAGS));
        tgcn_split<<<128, 256, 0, stream>>>(x, ws, clsw, clsb, outp);
    } else {
        tgcn_main<<<64, NTHREADS, 0, stream>>>(x, ws, clsw, clsb, outp);
    }
}

// Round 12
// 10067.730 us; speedup vs baseline: 2.2173x; 1.0014x over previous
//
#include <hip/hip_runtime.h>
#include <hip/hip_bf16.h>

// TGCN: B=64, T=500, N=21, HID=128.
// Round 19: r18 layer-split (10.08ms) + handoff de-serialization.
//   r18 counters: ring traffic goes through DRAM (WRITE 386MB = ring mirror,
//   FETCH 202MB = ring reads); tick 20us vs B compute floor ~12us. The gap is
//   protocol serialization (2-slot lockstep + in-tick DRAM stage latency).
//   Changes (compute phases VERBATIM r18 -> bit-exact, absmax 0.0):
//   (1) ring depth 4 when ws_size allows (else 2; else r16 fallback);
//   (2) B stage is issue-early/write-late: issue ring loads for k+1 after
//       P3(k), drain after P4(k) (8us of weight streaming hides DRAM latency);
//   (3) A back-pressure generalized to backp >= s-rdepth+1.
// NEVER reorder per-element sums in the recurrence.

#define NN 21
#define NROW 24            // padded rows (21,22,23 zero)
#define HID 128
#define TSTEPS 500
#define EDGES 210
#define RPT 6              // rows per wave (4 waves per group)

// ws layout (float offsets)
#define WS_A     0        // NROW*NN floats (pad rows zeroed on build)
#define WS_VEC   1600     // 9*128
#define WS_LZR1  3200     // 32*256 float4
#define WS_LH1   36000    // 32*128 float4
#define WS_WE2   52400    // 32*384 float4
#define WS_LZR2  101600   // 32*256 float4
#define WS_LH2   134400   // 32*128 float4 -> ends 150784
#define WS_FLAGS 150784   // 4096 uints: fwd[b] at +b*32, back[b] at +2048+b*32
#define WS_RING  154880   // 64 batches x rdepth slots x 3072 floats
#define RING_SLOT 3072    // NROW*HID

#define WAVE_SYNC() asm volatile("s_waitcnt lgkmcnt(0)" ::: "memory")
#define VM_SYNC()   asm volatile("s_waitcnt vmcnt(0)" ::: "memory")

typedef float v2f __attribute__((ext_vector_type(2)));

__device__ __forceinline__ v2f lo2(float4 w) { v2f v = {w.x, w.y}; return v; }
__device__ __forceinline__ v2f hi2(float4 w) { v2f v = {w.z, w.w}; return v; }
__device__ __forceinline__ void pkf(v2f& acc, float s, v2f w) {
    v2f ss = {s, s};
    acc = __builtin_elementwise_fma(ss, w, acc);
}
__device__ __forceinline__ float sigmoidf(float v) {
    return 1.0f / (1.0f + expf(-v));
}
// device-coherent scalar store (reaches the device coherence point)
__device__ __forceinline__ void dc_store(float* p, float v) {
    asm volatile("global_store_dword %0, %1, off sc0 sc1" :: "v"(p), "v"(v) : "memory");
}

// ---- Prologue: build normalized adjacency A (21x21) in fp64, store fp32 ----
__global__ void build_A(const int* __restrict__ ei, const float* __restrict__ ew,
                        float* __restrict__ Aout) {
    __shared__ double deg[NN];
    __shared__ double dinv[NN];
    __shared__ double Asm[NN * NN];
    int t = threadIdx.x;
    for (int k = t; k < NN * NN; k += blockDim.x) Asm[k] = 0.0;
    if (t < NN) deg[t] = 1.0;  // self loop weight 1
    __syncthreads();
    if (t == 0) {
        for (int e = 0; e < EDGES; e++) deg[ei[EDGES + e]] += (double)ew[e];
        for (int i = 0; i < NN; i++) dinv[i] = deg[i] > 0.0 ? 1.0 / sqrt(deg[i]) : 0.0;
        for (int e = 0; e < EDGES; e++) {
            int s = ei[e], d = ei[EDGES + e];
            Asm[d * NN + s] += dinv[s] * (double)ew[e] * dinv[d];
        }
        for (int i = 0; i < NN; i++) Asm[i * NN + i] += dinv[i] * dinv[i];
    }
    __syncthreads();
    for (int k = t; k < NROW * NN; k += blockDim.x)
        Aout[k] = (k < NN * NN) ? (float)Asm[k] : 0.0f;
}

__global__ void init_flags(unsigned* f) {
    int i = blockIdx.x * blockDim.x + threadIdx.x;
    if (i < 4096) f[i] = 0u;
}

// ---- Prologue: repack bottom halves of (256,128) concat weights ----------
__global__ void pack_bot(const float* __restrict__ w0, const float* __restrict__ w1,
                         float4* __restrict__ out, int ngate) {
    int t = blockIdx.x * blockDim.x + threadIdx.x;
    int per_c = ngate * 128;
    int total = 32 * per_c;
    if (t >= total) return;
    int c = t / per_c, rem = t - c * per_c;
    int gate = rem >> 7;
    int r2 = rem & 127;
    int k2 = r2 >> 6;
    int f0 = r2 & 63;
    int k = 4 * c + 2 * k2;
    const float* src = (gate == 0) ? w0 : w1;
    float4 v;
    v.x = src[(128 + k) * 128 + f0];
    v.y = src[(128 + k) * 128 + f0 + 64];
    v.z = src[(128 + k + 1) * 128 + f0];
    v.w = src[(128 + k + 1) * 128 + f0 + 64];
    out[t] = v;
}

// ---- Prologue: Weff2_g = Wg_2 @ lgw_2_top, pair-interleaved, fp64 accum ----
__global__ void make_weff2(const float* __restrict__ Wz2, const float* __restrict__ Wr2,
                           const float* __restrict__ Wh2,
                           const float* __restrict__ lzw2, const float* __restrict__ lrw2,
                           const float* __restrict__ lhw2,
                           float4* __restrict__ out) {
    int t = blockIdx.x * blockDim.x + threadIdx.x;
    if (t >= 32 * 384) return;
    int c = t / 384, rem = t - c * 384;
    int g = rem >> 7;
    int r2 = rem & 127;
    int k2 = r2 >> 6;
    int f0 = r2 & 63;
    int k = 4 * c + 2 * k2;
    const float* W = (g == 0) ? Wz2 : (g == 1) ? Wr2 : Wh2;
    const float* L = (g == 0) ? lzw2 : (g == 1) ? lrw2 : lhw2;
    double a0 = 0, a1 = 0, a2 = 0, a3 = 0;
    for (int m = 0; m < 128; m++) {
        double w0 = (double)W[k * 128 + m];
        double w1 = (double)W[(k + 1) * 128 + m];
        a0 += w0 * (double)L[m * 128 + f0];
        a1 += w0 * (double)L[m * 128 + f0 + 64];
        a2 += w1 * (double)L[m * 128 + f0];
        a3 += w1 * (double)L[m * 128 + f0 + 64];
    }
    out[t] = make_float4((float)a0, (float)a1, (float)a2, (float)a3);
}

// ---- Prologue: layer-1 effective row vectors + all bias consts (fp64) ----
__global__ void make_vecs(const float* __restrict__ Wz1, const float* __restrict__ Wr1,
                          const float* __restrict__ Wh1,
                          const float* __restrict__ bz1, const float* __restrict__ br1,
                          const float* __restrict__ bh1,
                          const float* __restrict__ lzw1, const float* __restrict__ lrw1,
                          const float* __restrict__ lhw1,
                          const float* __restrict__ lzb1, const float* __restrict__ lrb1,
                          const float* __restrict__ lhb1,
                          const float* __restrict__ bz2, const float* __restrict__ br2,
                          const float* __restrict__ bh2,
                          const float* __restrict__ lzw2, const float* __restrict__ lrw2,
                          const float* __restrict__ lhw2,
                          const float* __restrict__ lzb2, const float* __restrict__ lrb2,
                          const float* __restrict__ lhb2,
                          float* __restrict__ out) {
    int t = blockIdx.x * blockDim.x + threadIdx.x;
    if (t >= 9 * 128) return;
    int v = t >> 7, f = t & 127;
    double acc = 0.0;
    if (v < 3) {
        const float* W = (v == 0) ? Wz1 : (v == 1) ? Wr1 : Wh1;
        const float* L = (v == 0) ? lzw1 : (v == 1) ? lrw1 : lhw1;
        for (int m = 0; m < 128; m++) acc += (double)W[m] * (double)L[m * 128 + f];
    } else if (v < 6) {
        int g = v - 3;
        const float* bb = (g == 0) ? bz1 : (g == 1) ? br1 : bh1;
        const float* L  = (g == 0) ? lzw1 : (g == 1) ? lrw1 : lhw1;
        const float* lb = (g == 0) ? lzb1 : (g == 1) ? lrb1 : lhb1;
        for (int m = 0; m < 128; m++) acc += (double)bb[m] * (double)L[m * 128 + f];
        acc += (double)lb[f];
    } else {
        int g = v - 6;
        const float* bb = (g == 0) ? bz2 : (g == 1) ? br2 : bh2;
        const float* L  = (g == 0) ? lzw2 : (g == 1) ? lrw2 : lhw2;
        const float* lb = (g == 0) ? lzb2 : (g == 1) ? lrb2 : lhb2;
        for (int m = 0; m < 128; m++) acc += (double)bb[m] * (double)L[m * 128 + f];
        acc += (double)lb[f];
    }
    out[t] = (float)acc;
}

// ================= split kernel: 128 blocks x 256 threads =================
__global__ __launch_bounds__(256, 1) void tgcn_split(
    const float* __restrict__ x, float* __restrict__ ws,
    const float* __restrict__ cls_w, const float* __restrict__ cls_b,
    float* __restrict__ out, int rdepth)
{
    const int bid = blockIdx.x;
    const bool roleA = (bid < 64);
    const int b  = bid & 63;
    const int t  = threadIdx.x;
    const int f0 = t & 63;
    const int f1 = f0 + 64;
    const int gw = __builtin_amdgcn_readfirstlane(t >> 6);  // 0..3
    const int iA = gw * RPT;
    const int nreal = (iA + RPT <= NN) ? RPT : (NN - iA);
    const int dmask = rdepth - 1;   // rdepth is 2 or 4 (pow2)

    unsigned* fwdp  = (unsigned*)(ws + WS_FLAGS) + b * 32;
    unsigned* backp = (unsigned*)(ws + WS_FLAGS) + 2048 + b * 32;
    float* ringB = ws + WS_RING + (size_t)b * ((size_t)rdepth * RING_SLOT);

    // ---- LDS (A-role and B-role sets; both fit; 1 block/CU) ----
    __shared__ __align__(16) float sH1[2][NROW * HID];   // A: double-buffered state
    __shared__ __align__(16) float sHR1[NROW * HID];     // A
    __shared__ __align__(16) float sH1B[2][NROW * HID];  // B: staged H1, dbuf
    __shared__ __align__(16) float sH2[NROW * HID];      // B
    __shared__ __align__(16) float sHR2[NROW * HID];     // B
    __shared__ __align__(16) float sAH[NROW * HID];      // B
    __shared__ float sA[NROW * NN];
    __shared__ float sax[2][NROW];                       // A
    __shared__ double sred[4][HID];                      // B

    const float*  vecs = ws + WS_VEC;
    const float4* Lzr1 = (const float4*)(ws + WS_LZR1);
    const float4* Lh1  = (const float4*)(ws + WS_LH1);
    const float4* We2  = (const float4*)(ws + WS_WE2);
    const float4* Lzr2 = (const float4*)(ws + WS_LZR2);
    const float4* Lh2  = (const float4*)(ws + WS_LH2);

    const float4* HR1v = (const float4*)sHR1;
    const float4* HR2v = (const float4*)sHR2;
    const float4* AHv  = (const float4*)sAH;
    const float4* H2v  = (const float4*)sH2;

    for (int k = t; k < 2 * NROW * HID; k += 256) {
        ((float*)sH1)[k] = 0.0f;
        ((float*)sH1B)[k] = 0.0f;
    }
    for (int k = t; k < NROW * HID; k += 256) {
        sH2[k] = 0.0f; sHR1[k] = 0.0f; sHR2[k] = 0.0f; sAH[k] = 0.0f;
    }
    for (int k = t; k < NROW * NN; k += 256) sA[k] = ws[WS_A + k];

    // per-column-pair constants (registers; same as r16)
    const v2f wz1v = {vecs[f0],        vecs[f1]};
    const v2f wr1v = {vecs[128 + f0],  vecs[128 + f1]};
    const v2f wh1v = {vecs[256 + f0],  vecs[256 + f1]};
    const v2f cz1v = {vecs[384 + f0],  vecs[384 + f1]};
    const v2f cr1v = {vecs[512 + f0],  vecs[512 + f1]};
    const v2f ch1v = {vecs[640 + f0],  vecs[640 + f1]};
    const v2f cz2v = {vecs[768 + f0],  vecs[768 + f1]};
    const v2f cr2v = {vecs[896 + f0],  vecs[896 + f1]};
    const v2f ch2v = {vecs[1024 + f0], vecs[1024 + f1]};

    __syncthreads();

    if (roleA) {
        // =================== A: layer-1 producer ===================
        const float* xb = x + (size_t)b * (TSTEPS * NN);
        if (t < NROW) {  // sax for steps 0 and 1
            float a0s = 0.0f, a1s = 0.0f;
            for (int j = 0; j < NN; j++) {
                a0s = fmaf(sA[t * NN + j], xb[j], a0s);
                a1s = fmaf(sA[t * NN + j], xb[NN + j], a1s);
            }
            sax[0][t] = a0s;
            sax[1][t] = a1s;
        }
        __syncthreads();

        for (int s = 0; s < TSTEPS; s++) {
            if (t == 0 && s >= rdepth) {   // slot reuse back-pressure
                while (__hip_atomic_load(backp, __ATOMIC_RELAXED,
                                         __HIP_MEMORY_SCOPE_AGENT) < (unsigned)(s - rdepth + 1))
                    __builtin_amdgcn_s_sleep(2);
            }
            __syncthreads();

            // ---- layer1(s): P1 + WAVE_SYNC + P2 (verbatim r16) + ring mirror ----
            {
                const float* H1rd = sH1[(s + 1) & 1];
                float*       H1wr = sH1[s & 1];
                const float4* H1c = (const float4*)H1rd;
                float* g = ringB + (s & dmask) * RING_SLOT;
                float axp[RPT];
                #pragma unroll
                for (int r = 0; r < RPT; r++) axp[r] = sax[s & 1][iA + r];
                v2f az[RPT], ar[RPT];
                #pragma unroll
                for (int r = 0; r < RPT; r++) {
                    az[r] = __builtin_elementwise_fma((v2f){axp[r], axp[r]}, wz1v, cz1v);
                    ar[r] = __builtin_elementwise_fma((v2f){axp[r], axp[r]}, wr1v, cr1v);
                }
                #pragma unroll 2
                for (int c = 0; c < 32; ++c) {
                    const float4 wz0 = Lzr1[c * 256 + f0];
                    const float4 wz1 = Lzr1[c * 256 + 64 + f0];
                    const float4 wr0 = Lzr1[c * 256 + 128 + f0];
                    const float4 wr1 = Lzr1[c * 256 + 192 + f0];
                    #pragma unroll
                    for (int r = 0; r < RPT; r++) {
                        const float4 h = H1c[(iA + r) * 32 + c];
                        pkf(az[r], h.x, lo2(wz0)); pkf(az[r], h.y, hi2(wz0));
                        pkf(az[r], h.z, lo2(wz1)); pkf(az[r], h.w, hi2(wz1));
                        pkf(ar[r], h.x, lo2(wr0)); pkf(ar[r], h.y, hi2(wr0));
                        pkf(ar[r], h.z, lo2(wr1)); pkf(ar[r], h.w, hi2(wr1));
                    }
                }
                v2f zg[RPT], h1c[RPT];
                #pragma unroll
                for (int r = 0; r < RPT; r++) {
                    zg[r].x = sigmoidf(az[r].x);
                    zg[r].y = sigmoidf(az[r].y);
                    const float r0 = sigmoidf(ar[r].x);
                    const float r1 = sigmoidf(ar[r].y);
                    h1c[r].x = H1rd[(iA + r) * HID + f0];
                    h1c[r].y = H1rd[(iA + r) * HID + f1];
                    sHR1[(iA + r) * HID + f0] = h1c[r].x * r0;
                    sHR1[(iA + r) * HID + f1] = h1c[r].y * r1;
                }
                WAVE_SYNC();
                v2f ah[RPT];
                #pragma unroll
                for (int r = 0; r < RPT; r++)
                    ah[r] = __builtin_elementwise_fma((v2f){axp[r], axp[r]}, wh1v, ch1v);
                #pragma unroll 2
                for (int c = 0; c < 32; ++c) {
                    const float4 wh0 = Lh1[c * 128 + f0];
                    const float4 wh1 = Lh1[c * 128 + 64 + f0];
                    #pragma unroll
                    for (int r = 0; r < RPT; r++) {
                        const float4 q = HR1v[(iA + r) * 32 + c];
                        pkf(ah[r], q.x, lo2(wh0)); pkf(ah[r], q.y, hi2(wh0));
                        pkf(ah[r], q.z, lo2(wh1)); pkf(ah[r], q.w, hi2(wh1));
                    }
                }
                #pragma unroll
                for (int r = 0; r < RPT; r++) {
                    const int row = iA + r;
                    const float n0 = fmaf(zg[r].x, h1c[r].x, (1.0f - zg[r].x) * tanhf(ah[r].x));
                    const float n1 = fmaf(zg[r].y, h1c[r].y, (1.0f - zg[r].y) * tanhf(ah[r].y));
                    H1wr[row * HID + f0] = n0;
                    H1wr[row * HID + f1] = n1;
                    dc_store(g + row * HID + f0, n0);   // device-coherent mirror
                    dc_store(g + row * HID + f1, n1);
                }
            }
            // sax prefetch for step s+2 (wave 0)
            if (t < NROW && s + 2 < TSTEPS) {
                const float* xt = xb + (size_t)(s + 2) * NN;
                float a = 0.0f;
                for (int j = 0; j < NN; j++) a = fmaf(sA[t * NN + j], xt[j], a);
                sax[(s + 2) & 1][t] = a;
            }
            VM_SYNC();         // all mirror stores device-visible
            __syncthreads();
            if (t == 0)
                __hip_atomic_store(fwdp, (unsigned)(s + 1), __ATOMIC_RELAXED,
                                   __HIP_MEMORY_SCOPE_AGENT);
        }
        return;
    }

    // =================== B: layer-2 consumer ===================
    double oacc0 = 0.0, oacc1 = 0.0;
    v2f ph[RPT], z2[RPT], h2c[RPT];   // carried P4 -> P5

    auto l2_p5 = [&]() {
        #pragma unroll 2
        for (int c = 0; c < 32; ++c) {
            const float4 lh0 = Lh2[c * 128 + f0];
            const float4 lh1 = Lh2[c * 128 + 64 + f0];
            #pragma unroll
            for (int r = 0; r < RPT; r++) {
                const float4 q = HR2v[(iA + r) * 32 + c];
                pkf(ph[r], q.x, lo2(lh0)); pkf(ph[r], q.y, hi2(lh0));
                pkf(ph[r], q.z, lo2(lh1)); pkf(ph[r], q.w, hi2(lh1));
            }
        }
        #pragma unroll
        for (int r = 0; r < RPT; r++) {
            const float m0 = fmaf(z2[r].x, h2c[r].x, (1.0f - z2[r].x) * tanhf(ph[r].x));
            const float m1 = fmaf(z2[r].y, h2c[r].y, (1.0f - z2[r].y) * tanhf(ph[r].y));
            sH2[(iA + r) * HID + f0] = m0;
            sH2[(iA + r) * HID + f1] = m1;
            if (r < nreal) {
                oacc0 += (double)m0;
                oacc1 += (double)m1;
            }
        }
    };

    // ---- prologue: stage H1(0) into sH1B[0] ----
    {
        if (t == 0) {
            while (__hip_atomic_load(fwdp, __ATOMIC_RELAXED,
                                     __HIP_MEMORY_SCOPE_AGENT) < 1u)
                __builtin_amdgcn_s_sleep(2);
        }
        __syncthreads();
        const float4* gs = (const float4*)(ringB + 0 * RING_SLOT);
        const float4* p0 = gs + t;
        const float4* p1 = gs + t + 256;
        const float4* p2 = gs + t + 512;
        float4 v0, v1, v2;
        asm volatile(
            "global_load_dwordx4 %0, %3, off sc0 sc1\n\t"
            "global_load_dwordx4 %1, %4, off sc0 sc1\n\t"
            "global_load_dwordx4 %2, %5, off sc0 sc1\n\t"
            "s_waitcnt vmcnt(0)"
            : "=v"(v0), "=v"(v1), "=v"(v2)
            : "v"(p0), "v"(p1), "v"(p2)
            : "memory");
        float4* sB = (float4*)sH1B[0];
        sB[t] = v0; sB[t + 256] = v1; sB[t + 512] = v2;
        __syncthreads();
        if (t == 0)
            __hip_atomic_store(backp, 1u, __ATOMIC_RELAXED,
                               __HIP_MEMORY_SCOPE_AGENT);
    }

    for (int k = 0; k < TSTEPS; k++) {
        const float* H1k = sH1B[k & 1];
        // ---- P3: AH = A @ H1(k) ----
        {
            v2f aa[RPT];
            #pragma unroll
            for (int r = 0; r < RPT; r++) aa[r] = (v2f){0.0f, 0.0f};
            #pragma unroll 3
            for (int j = 0; j < NN; j++) {
                const v2f hj = {H1k[j * HID + f0], H1k[j * HID + f1]};
                #pragma unroll
                for (int r = 0; r < RPT; r++) {
                    const float arj = sA[(iA + r) * NN + j];
                    aa[r] = __builtin_elementwise_fma((v2f){arj, arj}, hj, aa[r]);
                }
            }
            #pragma unroll
            for (int r = 0; r < RPT; r++) {
                sAH[(iA + r) * HID + f0] = aa[r].x;
                sAH[(iA + r) * HID + f1] = aa[r].y;
            }
        }
        WAVE_SYNC();
        // ---- prefetch stage for k+1: issue loads now, drain after P4 ----
        const bool pf = (k + 1 < TSTEPS);
        float4 v0, v1, v2;
        if (pf) {
            if (t == 0) {
                while (__hip_atomic_load(fwdp, __ATOMIC_RELAXED,
                                         __HIP_MEMORY_SCOPE_AGENT) < (unsigned)(k + 2))
                    __builtin_amdgcn_s_sleep(2);
            }
            __syncthreads();   // flag confirmed for all threads
            const float4* gs = (const float4*)(ringB + ((k + 1) & dmask) * RING_SLOT);
            const float4* p0 = gs + t;
            const float4* p1 = gs + t + 256;
            const float4* p2 = gs + t + 512;
            asm volatile(
                "global_load_dwordx4 %0, %3, off sc0 sc1\n\t"
                "global_load_dwordx4 %1, %4, off sc0 sc1\n\t"
                "global_load_dwordx4 %2, %5, off sc0 sc1"
                : "=v"(v0), "=v"(v1), "=v"(v2)
                : "v"(p0), "v"(p1), "v"(p2)
                : "memory");
        }
        // ---- P4: layer-2 gcn + z,r gates (verbatim r16; hides ring latency) --
        {
            v2f pz[RPT], pr[RPT];
            #pragma unroll
            for (int r = 0; r < RPT; r++) { pz[r] = cz2v; pr[r] = cr2v; ph[r] = ch2v; }
            for (int c = 0; c < 32; ++c) {
                const float4 wz0 = We2[c * 384 + f0];
                const float4 wz1 = We2[c * 384 + 64 + f0];
                const float4 wr0 = We2[c * 384 + 128 + f0];
                const float4 wr1 = We2[c * 384 + 192 + f0];
                const float4 wh0 = We2[c * 384 + 256 + f0];
                const float4 wh1 = We2[c * 384 + 320 + f0];
                const float4 lz0 = Lzr2[c * 256 + f0];
                const float4 lz1 = Lzr2[c * 256 + 64 + f0];
                const float4 lr0 = Lzr2[c * 256 + 128 + f0];
                const float4 lr1 = Lzr2[c * 256 + 192 + f0];
                #pragma unroll
                for (int r = 0; r < RPT; r++) {
                    const float4 a = AHv[(iA + r) * 32 + c];
                    const float4 q = H2v[(iA + r) * 32 + c];
                    pkf(pz[r], a.x, lo2(wz0)); pkf(pz[r], a.y, hi2(wz0));
                    pkf(pz[r], a.z, lo2(wz1)); pkf(pz[r], a.w, hi2(wz1));
                    pkf(pz[r], q.x, lo2(lz0)); pkf(pz[r], q.y, hi2(lz0));
                    pkf(pz[r], q.z, lo2(lz1)); pkf(pz[r], q.w, hi2(lz1));
                    pkf(pr[r], a.x, lo2(wr0)); pkf(pr[r], a.y, hi2(wr0));
                    pkf(pr[r], a.z, lo2(wr1)); pkf(pr[r], a.w, hi2(wr1));
                    pkf(pr[r], q.x, lo2(lr0)); pkf(pr[r], q.y, hi2(lr0));
                    pkf(pr[r], q.z, lo2(lr1)); pkf(pr[r], q.w, hi2(lr1));
                    pkf(ph[r], a.x, lo2(wh0)); pkf(ph[r], a.y, hi2(wh0));
                    pkf(ph[r], a.z, lo2(wh1)); pkf(ph[r], a.w, hi2(wh1));
                }
            }
            #pragma unroll
            for (int r = 0; r < RPT; r++) {
                z2[r].x = sigmoidf(pz[r].x);
                z2[r].y = sigmoidf(pz[r].y);
                const float r20 = sigmoidf(pr[r].x);
                const float r21 = sigmoidf(pr[r].y);
                h2c[r].x = sH2[(iA + r) * HID + f0];
                h2c[r].y = sH2[(iA + r) * HID + f1];
                sHR2[(iA + r) * HID + f0] = h2c[r].x * r20;
                sHR2[(iA + r) * HID + f1] = h2c[r].y * r21;
            }
        }
        WAVE_SYNC();
        // ---- drain + publish staged H1(k+1), ack ring slot ----
        if (pf) {
            asm volatile("s_waitcnt vmcnt(0)" ::: "memory");
            __builtin_amdgcn_sched_barrier(0);
            float4* sB = (float4*)sH1B[(k + 1) & 1];
            sB[t] = v0; sB[t + 256] = v1; sB[t + 512] = v2;
            __syncthreads();   // publish to all waves (next tick's P3)
            if (t == 0)
                __hip_atomic_store(backp, (unsigned)(k + 2), __ATOMIC_RELAXED,
                                   __HIP_MEMORY_SCOPE_AGENT);
        }
        // ---- P5: layer-2 h gate finish + H2 update + output accum ----
        l2_p5();
    }

    // ---------- Epilogue: mean, cls ----------
    sred[gw][f0] = oacc0;
    sred[gw][f1] = oacc1;
    __syncthreads();
    if (t < HID) {
        double s = 0.0;
        for (int gg = 0; gg < 4; gg++) s += sred[gg][t];
        sred[0][t] = (s / (double)(TSTEPS * NN)) * (double)cls_w[t];
    }
    __syncthreads();
    if (t < 64) {
        double v = ((double*)sred)[t] + ((double*)sred)[t + 64];
        for (int off = 32; off; off >>= 1) v += __shfl_down(v, off, 64);
        if (t == 0) out[b] = (float)(v + (double)cls_b[0]);
    }
}

// ================= fallback: r16 single-block kernel (proven 12.5ms) ========
#define NTHREADS 512
__global__ __launch_bounds__(NTHREADS, 1) void tgcn_main(
    const float* __restrict__ x, const float* __restrict__ ws,
    const float* __restrict__ cls_w, const float* __restrict__ cls_b,
    float* __restrict__ out)
{
    const int b  = blockIdx.x;
    const int t  = threadIdx.x;
    const bool isA = (t < 256);
    const int lt = t & 255;
    const int f0 = lt & 63;
    const int f1 = f0 + 64;
    const int gw = __builtin_amdgcn_readfirstlane(lt >> 6);
    const int iA = gw * RPT;
    const int nreal = (iA + RPT <= NN) ? RPT : (NN - iA);

    __shared__ __align__(16) float sH1[2][NROW * HID];
    __shared__ __align__(16) float sH2[NROW * HID];
    __shared__ __align__(16) float sHR1[NROW * HID];
    __shared__ __align__(16) float sHR2[NROW * HID];
    __shared__ __align__(16) float sAH[NROW * HID];
    __shared__ float sA[NROW * NN];
    __shared__ float sax[2][NROW];
    __shared__ double sred[4][HID];

    const float*  vecs = ws + WS_VEC;
    const float4* Lzr1 = (const float4*)(ws + WS_LZR1);
    const float4* Lh1  = (const float4*)(ws + WS_LH1);
    const float4* We2  = (const float4*)(ws + WS_WE2);
    const float4* Lzr2 = (const float4*)(ws + WS_LZR2);
    const float4* Lh2  = (const float4*)(ws + WS_LH2);

    const float4* H2v  = (const float4*)sH2;
    const float4* HR1v = (const float4*)sHR1;
    const float4* HR2v = (const float4*)sHR2;
    const float4* AHv  = (const float4*)sAH;

    for (int k = t; k < 2 * NROW * HID; k += NTHREADS) ((float*)sH1)[k] = 0.0f;
    for (int k = t; k < NROW * HID; k += NTHREADS) sH2[k] = 0.0f;
    for (int k = t; k < NROW * NN; k += NTHREADS) sA[k] = ws[WS_A + k];

    const v2f wz1v = {vecs[f0],        vecs[f1]};
    const v2f wr1v = {vecs[128 + f0],  vecs[128 + f1]};
    const v2f wh1v = {vecs[256 + f0],  vecs[256 + f1]};
    const v2f cz1v = {vecs[384 + f0],  vecs[384 + f1]};
    const v2f cr1v = {vecs[512 + f0],  vecs[512 + f1]};
    const v2f ch1v = {vecs[640 + f0],  vecs[640 + f1]};
    const v2f cz2v = {vecs[768 + f0],  vecs[768 + f1]};
    const v2f cr2v = {vecs[896 + f0],  vecs[896 + f1]};
    const v2f ch2v = {vecs[1024 + f0], vecs[1024 + f1]};

    __syncthreads();

    const float* xb = x + (size_t)b * (TSTEPS * NN);
    if (t < NROW) {
        float a0s = 0.0f, a1s = 0.0f;
        for (int j = 0; j < NN; j++) {
            a0s = fmaf(sA[t * NN + j], xb[j], a0s);
            a1s = fmaf(sA[t * NN + j], xb[NN + j], a1s);
        }
        sax[0][t] = a0s;
        sax[1][t] = a1s;
    }
    __syncthreads();

    double oacc0 = 0.0, oacc1 = 0.0;

    auto layer1 = [&](int s) {
        const float* H1rd = sH1[(s + 1) & 1];
        float*       H1wr = sH1[s & 1];
        const float4* H1c = (const float4*)H1rd;
        float axp[RPT];
        #pragma unroll
        for (int r = 0; r < RPT; r++) axp[r] = sax[s & 1][iA + r];
        v2f az[RPT], ar[RPT];
        #pragma unroll
        for (int r = 0; r < RPT; r++) {
            az[r] = __builtin_elementwise_fma((v2f){axp[r], axp[r]}, wz1v, cz1v);
            ar[r] = __builtin_elementwise_fma((v2f){axp[r], axp[r]}, wr1v, cr1v);
        }
        #pragma unroll 2
        for (int c = 0; c < 32; ++c) {
            const float4 wz0 = Lzr1[c * 256 + f0];
            const float4 wz1 = Lzr1[c * 256 + 64 + f0];
            const float4 wr0 = Lzr1[c * 256 + 128 + f0];
            const float4 wr1 = Lzr1[c * 256 + 192 + f0];
            #pragma unroll
            for (int r = 0; r < RPT; r++) {
                const float4 h = H1c[(iA + r) * 32 + c];
                pkf(az[r], h.x, lo2(wz0)); pkf(az[r], h.y, hi2(wz0));
                pkf(az[r], h.z, lo2(wz1)); pkf(az[r], h.w, hi2(wz1));
                pkf(ar[r], h.x, lo2(wr0)); pkf(ar[r], h.y, hi2(wr0));
                pkf(ar[r], h.z, lo2(wr1)); pkf(ar[r], h.w, hi2(wr1));
            }
        }
        v2f zg[RPT], h1c[RPT];
        #pragma unroll
        for (int r = 0; r < RPT; r++) {
            zg[r].x = sigmoidf(az[r].x);
            zg[r].y = sigmoidf(az[r].y);
            const float r0 = sigmoidf(ar[r].x);
            const float r1 = sigmoidf(ar[r].y);
            h1c[r].x = H1rd[(iA + r) * HID + f0];
            h1c[r].y = H1rd[(iA + r) * HID + f1];
            sHR1[(iA + r) * HID + f0] = h1c[r].x * r0;
            sHR1[(iA + r) * HID + f1] = h1c[r].y * r1;
        }
        WAVE_SYNC();
        v2f ah[RPT];
        #pragma unroll
        for (int r = 0; r < RPT; r++)
            ah[r] = __builtin_elementwise_fma((v2f){axp[r], axp[r]}, wh1v, ch1v);
        #pragma unroll 2
        for (int c = 0; c < 32; ++c) {
            const float4 wh0 = Lh1[c * 128 + f0];
            const float4 wh1 = Lh1[c * 128 + 64 + f0];
            #pragma unroll
            for (int r = 0; r < RPT; r++) {
                const float4 q = HR1v[(iA + r) * 32 + c];
                pkf(ah[r], q.x, lo2(wh0)); pkf(ah[r], q.y, hi2(wh0));
                pkf(ah[r], q.z, lo2(wh1)); pkf(ah[r], q.w, hi2(wh1));
            }
        }
        #pragma unroll
        for (int r = 0; r < RPT; r++) {
            const float n0 = fmaf(zg[r].x, h1c[r].x, (1.0f - zg[r].x) * tanhf(ah[r].x));
            const float n1 = fmaf(zg[r].y, h1c[r].y, (1.0f - zg[r].y) * tanhf(ah[r].y));
            H1wr[(iA + r) * HID + f0] = n0;
            H1wr[(iA + r) * HID + f1] = n1;
        }
    };

    if (isA) layer1(0);
    __syncthreads();

    for (int k = 0; k < TSTEPS; k++) {
        if (isA) {
            if (k + 1 < TSTEPS) {
                layer1(k + 1);
                if (t < NROW && k + 2 < TSTEPS) {
                    const float* xt = xb + (size_t)(k + 2) * NN;
                    float a = 0.0f;
                    for (int j = 0; j < NN; j++) a = fmaf(sA[t * NN + j], xt[j], a);
                    sax[(k + 2) & 1][t] = a;
                }
            }
        } else {
            const float* H1rd = sH1[k & 1];
            v2f aa[RPT];
            #pragma unroll
            for (int r = 0; r < RPT; r++) aa[r] = (v2f){0.0f, 0.0f};
            #pragma unroll 3
            for (int j = 0; j < NN; j++) {
                const v2f hj = {H1rd[j * HID + f0], H1rd[j * HID + f1]};
                #pragma unroll
                for (int r = 0; r < RPT; r++) {
                    const float arj = sA[(iA + r) * NN + j];
                    aa[r] = __builtin_elementwise_fma((v2f){arj, arj}, hj, aa[r]);
                }
            }
            #pragma unroll
            for (int r = 0; r < RPT; r++) {
                sAH[(iA + r) * HID + f0] = aa[r].x;
                sAH[(iA + r) * HID + f1] = aa[r].y;
            }
            WAVE_SYNC();
            v2f pz[RPT], pr[RPT], ph[RPT];
            #pragma unroll
            for (int r = 0; r < RPT; r++) { pz[r] = cz2v; pr[r] = cr2v; ph[r] = ch2v; }
            for (int c = 0; c < 32; ++c) {
                const float4 wz0 = We2[c * 384 + f0];
                const float4 wz1 = We2[c * 384 + 64 + f0];
                const float4 wr0 = We2[c * 384 + 128 + f0];
                const float4 wr1 = We2[c * 384 + 192 + f0];
                const float4 wh0 = We2[c * 384 + 256 + f0];
                const float4 wh1 = We2[c * 384 + 320 + f0];
                const float4 lz0 = Lzr2[c * 256 + f0];
                const float4 lz1 = Lzr2[c * 256 + 64 + f0];
                const float4 lr0 = Lzr2[c * 256 + 128 + f0];
                const float4 lr1 = Lzr2[c * 256 + 192 + f0];
                #pragma unroll
                for (int r = 0; r < RPT; r++) {
                    const float4 a = AHv[(iA + r) * 32 + c];
                    const float4 q = H2v[(iA + r) * 32 + c];
                    pkf(pz[r], a.x, lo2(wz0)); pkf(pz[r], a.y, hi2(wz0));
                    pkf(pz[r], a.z, lo2(wz1)); pkf(pz[r], a.w, hi2(wz1));
                    pkf(pz[r], q.x, lo2(lz0)); pkf(pz[r], q.y, hi2(lz0));
                    pkf(pz[r], q.z, lo2(lz1)); pkf(pz[r], q.w, hi2(lz1));
                    pkf(pr[r], a.x, lo2(wr0)); pkf(pr[r], a.y, hi2(wr0));
                    pkf(pr[r], a.z, lo2(wr1)); pkf(pr[r], a.w, hi2(wr1));
                    pkf(pr[r], q.x, lo2(lr0)); pkf(pr[r], q.y, hi2(lr0));
                    pkf(pr[r], q.z, lo2(lr1)); pkf(pr[r], q.w, hi2(lr1));
                    pkf(ph[r], a.x, lo2(wh0)); pkf(ph[r], a.y, hi2(wh0));
                    pkf(ph[r], a.z, lo2(wh1)); pkf(ph[r], a.w, hi2(wh1));
                }
            }
            v2f z2[RPT], h2c[RPT];
            #pragma unroll
            for (int r = 0; r < RPT; r++) {
                z2[r].x = sigmoidf(pz[r].x);
                z2[r].y = sigmoidf(pz[r].y);
                const float r20 = sigmoidf(pr[r].x);
                const float r21 = sigmoidf(pr[r].y);
                h2c[r].x = sH2[(iA + r) * HID + f0];
                h2c[r].y = sH2[(iA + r) * HID + f1];
                sHR2[(iA + r) * HID + f0] = h2c[r].x * r20;
                sHR2[(iA + r) * HID + f1] = h2c[r].y * r21;
            }
            WAVE_SYNC();
            #pragma unroll 2
            for (int c = 0; c < 32; ++c) {
                const float4 lh0 = Lh2[c * 128 + f0];
                const float4 lh1 = Lh2[c * 128 + 64 + f0];
                #pragma unroll
                for (int r = 0; r < RPT; r++) {
                    const float4 q = HR2v[(iA + r) * 32 + c];
                    pkf(ph[r], q.x, lo2(lh0)); pkf(ph[r], q.y, hi2(lh0));
                    pkf(ph[r], q.z, lo2(lh1)); pkf(ph[r], q.w, hi2(lh1));
                }
            }
            #pragma unroll
            for (int r = 0; r < RPT; r++) {
                const float m0 = fmaf(z2[r].x, h2c[r].x, (1.0f - z2[r].x) * tanhf(ph[r].x));
                const float m1 = fmaf(z2[r].y, h2c[r].y, (1.0f - z2[r].y) * tanhf(ph[r].y));
                sH2[(iA + r) * HID + f0] = m0;
                sH2[(iA + r) * HID + f1] = m1;
                if (r < nreal) {
                    oacc0 += (double)m0;
                    oacc1 += (double)m1;
                }
            }
        }
        __syncthreads();
    }

    if (!isA) {
        sred[gw][f0] = oacc0;
        sred[gw][f1] = oacc1;
    }
    __syncthreads();
    if (t < HID) {
        double s = 0.0;
        for (int gg = 0; gg < 4; gg++) s += sred[gg][t];
        sred[0][t] = (s / (double)(TSTEPS * NN)) * (double)cls_w[t];
    }
    __syncthreads();
    if (t < 64) {
        double v = ((double*)sred)[t] + ((double*)sred)[t + 64];
        for (int off = 32; off; off >>= 1) v += __shfl_down(v, off, 64);
        if (t == 0) out[b] = (float)(v + (double)cls_b[0]);
    }
}

extern "C" void kernel_launch(void* const* d_in, const int* in_sizes, int n_in,
                              void* d_out, int out_size, void* d_ws, size_t ws_size,
                              hipStream_t stream) {
    const float* x    = (const float*)d_in[0];
    const int*   ei   = (const int*)  d_in[1];
    const float* ew   = (const float*)d_in[2];
    const float* Wz1  = (const float*)d_in[3];
    const float* bz1  = (const float*)d_in[4];
    const float* lzw1 = (const float*)d_in[5];
    const float* lzb1 = (const float*)d_in[6];
    const float* Wr1  = (const float*)d_in[7];
    const float* br1  = (const float*)d_in[8];
    const float* lrw1 = (const float*)d_in[9];
    const float* lrb1 = (const float*)d_in[10];
    const float* Wh1  = (const float*)d_in[11];
    const float* bh1  = (const float*)d_in[12];
    const float* lhw1 = (const float*)d_in[13];
    const float* lhb1 = (const float*)d_in[14];
    const float* Wz2  = (const float*)d_in[15];
    const float* bz2  = (const float*)d_in[16];
    const float* lzw2 = (const float*)d_in[17];
    const float* lzb2 = (const float*)d_in[18];
    const float* Wr2  = (const float*)d_in[19];
    const float* br2  = (const float*)d_in[20];
    const float* lrw2 = (const float*)d_in[21];
    const float* lrb2 = (const float*)d_in[22];
    const float* Wh2  = (const float*)d_in[23];
    const float* bh2  = (const float*)d_in[24];
    const float* lhw2 = (const float*)d_in[25];
    const float* lhb2 = (const float*)d_in[26];
    const float* clsw = (const float*)d_in[27];
    const float* clsb = (const float*)d_in[28];

    float* ws   = (float*)d_ws;
    float* outp = (float*)d_out;

    build_A<<<1, 64, 0, stream>>>(ei, ew, ws + WS_A);
    pack_bot<<<32, 256, 0, stream>>>(lzw1, lrw1, (float4*)(ws + WS_LZR1), 2);
    pack_bot<<<16, 256, 0, stream>>>(lhw1, lhw1, (float4*)(ws + WS_LH1), 1);
    pack_bot<<<32, 256, 0, stream>>>(lzw2, lrw2, (float4*)(ws + WS_LZR2), 2);
    pack_bot<<<16, 256, 0, stream>>>(lhw2, lhw2, (float4*)(ws + WS_LH2), 1);
    make_weff2<<<48, 256, 0, stream>>>(Wz2, Wr2, Wh2, lzw2, lrw2, lhw2,
                                       (float4*)(ws + WS_WE2));
    make_vecs<<<5, 256, 0, stream>>>(Wz1, Wr1, Wh1, bz1, br1, bh1,
                                     lzw1, lrw1, lhw1, lzb1, lrb1, lhb1,
                                     bz2, br2, bh2, lzw2, lrw2, lhw2,
                                     lzb2, lrb2, lhb2, ws + WS_VEC);

    const size_t need4 = (size_t)(WS_RING + 64 * 4 * RING_SLOT) * sizeof(float);
    const size_t need2 = (size_t)(WS_RING + 64 * 2 * RING_SLOT) * sizeof(float);
    int rdepth = 0;
    if (ws_size >= need4)      rdepth = 4;
    else if (ws_size >= need2) rdepth = 2;

    if (rdepth) {
        init_flags<<<16, 256, 0, stream>>>((unsigned*)(ws + WS_FLAGS));
        tgcn_split<<<128, 256, 0, stream>>>(x, ws, clsw, clsb, outp, rdepth);
    } else {
        tgcn_main<<<64, NTHREADS, 0, stream>>>(x, ws, clsw, clsb, outp);
    }
}